// Round 6
// baseline (358.920 us; speedup 1.0000x reference)
//
#include <hip/hip_runtime.h>
#include <math.h>

#define GELU(v) (0.5f * (v) * (1.0f + erff((v)*0.70710678118654752440f)))

// ---------------- Setup: fold/transpose weights --------------------------------
// fwe2[grp(4)][ic(16)][k(9)][o(8)]            : enc2 transposed    (4608)
// fwd1[grp(2)][ic(32)][phase(4)][tap(4)][o(8)]: dec1 up2-folded    (8192)
// fwd2[ic(16)][phase(4)][tap(4)]              : dec2 up2-folded    (256)
__global__ __launch_bounds__(256) void k_fold(const float* __restrict__ e2w,
                                              const float* __restrict__ d1w,
                                              const float* __restrict__ d2w,
                                              float* __restrict__ fwe2,
                                              float* __restrict__ fwd1,
                                              float* __restrict__ fwd2) {
  int i = blockIdx.x * 256 + threadIdx.x;
  if (i < 4608) {
    int o = i & 7, k = (i >> 3) % 9, ic = (i / 72) & 15, grp = i / 1152;
    fwe2[i] = e2w[((grp * 8 + o) * 16 + ic) * 9 + k];
  } else if (i < 12800) {
    int j = i - 4608;
    int o = j & 7, pt = (j >> 3) & 15, ic = (j >> 7) & 31, grp = j >> 12;
    int a = pt >> 3, b2 = (pt >> 2) & 1, dy = (pt >> 1) & 1, dx = pt & 1;
    const float* wsrc = d1w + ((grp * 8 + o) * 32 + ic) * 9;
    float s = 0.f;
    for (int ky = 0; ky < 3; ++ky) {
      int rm = (a == 0) ? (ky == 0 ? 0 : 1) : (ky == 2 ? 1 : 0);
      if (rm != dy) continue;
      for (int kx = 0; kx < 3; ++kx) {
        int cm = (b2 == 0) ? (kx == 0 ? 0 : 1) : (kx == 2 ? 1 : 0);
        if (cm == dx) s += wsrc[ky * 3 + kx];
      }
    }
    fwd1[j] = s;
  } else if (i < 13056) {
    int j = i - 12800;
    int pt = j & 15, ic = j >> 4;
    int a = pt >> 3, b2 = (pt >> 2) & 1, dy = (pt >> 1) & 1, dx = pt & 1;
    const float* wsrc = d2w + ic * 9;
    float s = 0.f;
    for (int ky = 0; ky < 3; ++ky) {
      int rm = (a == 0) ? (ky == 0 ? 0 : 1) : (ky == 2 ? 1 : 0);
      if (rm != dy) continue;
      for (int kx = 0; kx < 3; ++kx) {
        int cm = (b2 == 0) ? (kx == 0 ? 0 : 1) : (kx == 2 ? 1 : 0);
        if (cm == dx) s += wsrc[ky * 3 + kx];
      }
    }
    fwd2[j] = s;
  }
}

// ---------------- Kernel A: conv1 (1->16) + maxpool2 + gelu --------------------
__global__ __launch_bounds__(256) void k_enc1(const float* __restrict__ x,
                                              const float* __restrict__ w,
                                              const float* __restrict__ bias,
                                              float* __restrict__ h1) {
  int gid = blockIdx.x * 256 + threadIdx.x;
  int xx = gid & 127, yy = (gid >> 7) & 127, b = gid >> 14;
  const float* xp = x + (size_t)b * 65536;
  int r0 = 2 * yy - 1, c0 = 2 * xx - 1;
  float in[4][4];
#pragma unroll
  for (int i = 0; i < 4; ++i) {
    int r = r0 + i;
    bool rv = (unsigned)r < 256u;
#pragma unroll
    for (int j = 0; j < 4; ++j) {
      int c = c0 + j;
      in[i][j] = (rv && (unsigned)c < 256u) ? xp[r * 256 + c] : 0.0f;
    }
  }
  float* op = h1 + (size_t)b * 262144 + yy * 128 + xx;
#pragma unroll
  for (int oc = 0; oc < 16; ++oc) {
    const float* wp = w + oc * 9;  // uniform -> s_load
    float s00 = 0.f, s01 = 0.f, s10 = 0.f, s11 = 0.f;
#pragma unroll
    for (int ky = 0; ky < 3; ++ky)
#pragma unroll
      for (int kx = 0; kx < 3; ++kx) {
        float wv = wp[ky * 3 + kx];
        s00 = fmaf(in[ky][kx], wv, s00);
        s01 = fmaf(in[ky][kx + 1], wv, s01);
        s10 = fmaf(in[ky + 1][kx], wv, s10);
        s11 = fmaf(in[ky + 1][kx + 1], wv, s11);
      }
    float m = fmaxf(fmaxf(s00, s01), fmaxf(s10, s11)) + bias[oc];
    op[oc * 16384] = GELU(m);
  }
}

// ---------------- Kernel B: conv2 (16->32) + maxpool2 --------------------------
// Ping-pong iv tile across ic: issue ic+1's ds_reads before ic's 72-FMA block.
__device__ __forceinline__ void e2_loadiv(float (&dst)[4][4], const float* t) {
#pragma unroll
  for (int dy = 0; dy < 4; ++dy)
#pragma unroll
    for (int dx = 0; dx < 4; ++dx)
      dst[dy][dx] = t[dy * 20 + (dx & 1) * 10 + (dx >> 1)];
}
__device__ __forceinline__ void e2_fma(float (&acc)[4][8], const float (&iv)[4][4],
                                       const float* wp) {
#pragma unroll
  for (int k = 0; k < 9; ++k) {
    int ky = k / 3, kx = k % 3;
#pragma unroll
    for (int o = 0; o < 8; ++o) {
      float wv = wp[k * 8 + o];
      acc[0][o] = fmaf(iv[ky][kx], wv, acc[0][o]);
      acc[1][o] = fmaf(iv[ky][kx + 1], wv, acc[1][o]);
      acc[2][o] = fmaf(iv[ky + 1][kx], wv, acc[2][o]);
      acc[3][o] = fmaf(iv[ky + 1][kx + 1], wv, acc[3][o]);
    }
  }
}
__global__ __launch_bounds__(256) void k_enc2(const float* __restrict__ h1,
                                              const float* __restrict__ fwe2,
                                              const float* __restrict__ bias,
                                              float* __restrict__ h2) {
  __shared__ float st[16 * 360];  // [ic][18 rows][20: evens 0-9, odds 10-19]
  int tid = threadIdx.x;
  int b = blockIdx.y;
  int Y0 = (blockIdx.x >> 3) * 8, X0 = (blockIdx.x & 7) * 8;
  int r_s = 2 * Y0 - 1, c_s = 2 * X0 - 1;
  const float* ip = h1 + (size_t)b * 262144;
  for (int i = tid; i < 5184; i += 256) {  // 16 ic x 18 x 18
    int ic = i / 324, rr = (i % 324) / 18, cc = i % 18;
    int r = r_s + rr, c = c_s + cc;
    float v = ((unsigned)r < 128u && (unsigned)c < 128u) ? ip[ic * 16384 + r * 128 + c] : 0.f;
    st[ic * 360 + rr * 20 + (cc & 1) * 10 + (cc >> 1)] = v;
  }
  __syncthreads();
  int lane = tid & 63;
  int grp = __builtin_amdgcn_readfirstlane(tid >> 6);
  int oc0 = grp * 8;
  int ty = lane >> 3, tx = lane & 7;
  float acc[4][8];
#pragma unroll
  for (int p = 0; p < 4; ++p)
#pragma unroll
    for (int o = 0; o < 8; ++o) acc[p][o] = 0.f;
  const float* wgrp = fwe2 + grp * 1152;  // scalar base
  const float* tb = st + (2 * ty) * 20 + tx;
  float ivA[4][4], ivB[4][4];
  e2_loadiv(ivA, tb);
#pragma unroll 1
  for (int ic = 0; ic < 16; ic += 2) {
    e2_loadiv(ivB, tb + (ic + 1) * 360);
    e2_fma(acc, ivA, wgrp + ic * 72);
    e2_loadiv(ivA, tb + ((ic + 2) & 15) * 360);  // wrap: harmless re-read
    e2_fma(acc, ivB, wgrp + (ic + 1) * 72);
  }
  float* op = h2 + (size_t)b * 131072 + (Y0 + ty) * 64 + X0 + tx;
#pragma unroll
  for (int o = 0; o < 8; ++o) {
    float m = fmaxf(fmaxf(acc[0][o], acc[1][o]), fmaxf(acc[2][o], acc[3][o])) + bias[oc0 + o];
    op[(oc0 + o) * 4096] = m;
  }
}

// ---------------- Kernel C1: VQ distance scan over a 128-code chunk ------------
// Delivery pipe: VMEM. The codebook base pointer is pinned into a VGPR by an
// empty opaque asm, defeating uniformity analysis -> loads compile to
// global_load_dwordx4 (1 coalesced 16B L1-hit per wave, broadcast). VMEM returns
// are in-order and per-register tracked, so the COMPILER inserts counted
// s_waitcnt vmcnt(N) for the A/B ping-pong (no manual ledger -> no r5 hazard).
// 2 tokens/thread: 64 FMAs cover each row's 8-load wait; 8 waves/CU x 8 req /
// 144 cyc = 0.44 req/cyc, under the ~1/cyc TA limit. Token floats pinned live
// via empty "+v" asm (blocks in-loop rematerialization seen in r0).
__global__ __launch_bounds__(256) void k_vq_chunk(const float* __restrict__ h2,
                                                  const float* __restrict__ cb,
                                                  float* __restrict__ dists,
                                                  int* __restrict__ idxs) {
  __shared__ float scsq[128];
  int tid = threadIdx.x;
  int chunk = blockIdx.x >> 8;
  int jbase = chunk << 7;
  if (tid < 128) {
    const float* row = cb + (size_t)(jbase + tid) * 32;
    float s = 0.f;
#pragma unroll
    for (int d = 0; d < 32; ++d) s = fmaf(row[d], row[d], s);
    scsq[tid] = s;
  }
  int gid = (blockIdx.x & 255) * 256 + tid;  // [0, 65536)
  int t0 = gid, t1 = gid + 65536;
  size_t a0 = (size_t)(t0 >> 12) * 131072 + (t0 & 4095);
  size_t a1 = (size_t)(t1 >> 12) * 131072 + (t1 & 4095);
  float f0[32], f1[32];
#pragma unroll
  for (int c = 0; c < 32; ++c) {
    f0[c] = h2[a0 + c * 4096];
    f1[c] = h2[a1 + c * 4096];
  }
#pragma unroll
  for (int c = 0; c < 32; ++c) {  // pin live: cannot be rematerialized
    asm volatile("" : "+v"(f0[c]));
    asm volatile("" : "+v"(f1[c]));
  }
  __syncthreads();

  const float* rb = cb + (size_t)jbase * 32;
  asm volatile("" : "+v"(rb));  // VGPR base -> VMEM loads (not s_load)
  const float4* r4 = (const float4*)rb;

  float best0 = 3.4e38f, best1 = 3.4e38f;
  int bi0 = jbase, bi1 = jbase;
  float4 A[8], B[8];
  float csqA, csqB;
#pragma unroll
  for (int q = 0; q < 8; ++q) A[q] = r4[q];
  csqA = scsq[0];

#define VQ_STEP(R, CSQ, JV)                                                    \
  {                                                                            \
    float s00 = 0.f, s01 = 0.f, s10 = 0.f, s11 = 0.f;                          \
    _Pragma("unroll") for (int q = 0; q < 8; ++q) {                            \
      float4 v = R[q];                                                         \
      s00 = fmaf(v.x, f0[4 * q + 0], s00); s01 = fmaf(v.y, f0[4 * q + 1], s01);\
      s00 = fmaf(v.z, f0[4 * q + 2], s00); s01 = fmaf(v.w, f0[4 * q + 3], s01);\
      s10 = fmaf(v.x, f1[4 * q + 0], s10); s11 = fmaf(v.y, f1[4 * q + 1], s11);\
      s10 = fmaf(v.z, f1[4 * q + 2], s10); s11 = fmaf(v.w, f1[4 * q + 3], s11);\
    }                                                                          \
    float d0 = (CSQ)-2.f * (s00 + s01);                                        \
    float d1 = (CSQ)-2.f * (s10 + s11);                                        \
    if (d0 < best0) { best0 = d0; bi0 = jbase + (JV); }                        \
    if (d1 < best1) { best1 = d1; bi1 = jbase + (JV); }                        \
  }

#pragma unroll 1
  for (int jl = 0; jl < 128; jl += 2) {
#pragma unroll
    for (int q = 0; q < 8; ++q) B[q] = r4[(jl + 1) * 8 + q];
    csqB = scsq[jl + 1];
    VQ_STEP(A, csqA, jl);
#pragma unroll
    for (int q = 0; q < 8; ++q) A[q] = r4[((jl + 2) & 127) * 8 + q];  // wrap: in-bounds
    csqA = scsq[(jl + 2) & 127];
    VQ_STEP(B, csqB, jl + 1);
  }
#undef VQ_STEP
  size_t cbase = (size_t)chunk * 131072;
  dists[cbase + t0] = best0;
  dists[cbase + t1] = best1;
  idxs[cbase + t0] = bi0;
  idxs[cbase + t1] = bi1;
}

// ---------------- Kernel C2: merge 4 chunk candidates, quantize, loss ----------
__global__ __launch_bounds__(256) void k_vq_merge(float* __restrict__ h2,
                                                  const float* __restrict__ cb,
                                                  const float* __restrict__ dists,
                                                  const int* __restrict__ idxs,
                                                  float* __restrict__ idxout,
                                                  float* __restrict__ partial) {
  __shared__ float sred[4];
  int tid = threadIdx.x;
  int t = blockIdx.x * 256 + tid;
  float bd = dists[t];
  int bi = idxs[t];
#pragma unroll
  for (int k = 1; k < 4; ++k) {
    float dk = dists[(size_t)k * 131072 + t];
    int ik = idxs[(size_t)k * 131072 + t];
    if (dk < bd) { bd = dk; bi = ik; }
  }
  size_t a = (size_t)(t >> 12) * 131072 + (t & 4095);
  const float* q = cb + (size_t)bi * 32;
  float loss = 0.f;
#pragma unroll
  for (int c = 0; c < 32; ++c) {
    float f = h2[a + c * 4096];
    float qv = q[c];
    h2[a + c * 4096] = qv;
    float dd = qv - f;
    loss = fmaf(dd, dd, loss);
  }
  idxout[t] = (float)bi;
#pragma unroll
  for (int off = 32; off > 0; off >>= 1) loss += __shfl_down(loss, off, 64);
  if ((tid & 63) == 0) sred[tid >> 6] = loss;
  __syncthreads();
  if (tid == 0) partial[blockIdx.x] = (sred[0] + sred[1]) + (sred[2] + sred[3]);
}

// ---------------- Kernel F: finalize commit loss (512 partials) ----------------
__global__ __launch_bounds__(256) void k_loss(const float* __restrict__ partial,
                                              float* __restrict__ lossout) {
  __shared__ float sred[4];
  int tid = threadIdx.x;
  float v = partial[tid] + partial[tid + 256];
#pragma unroll
  for (int off = 32; off > 0; off >>= 1) v += __shfl_down(v, off, 64);
  if ((tid & 63) == 0) sred[tid >> 6] = v;
  __syncthreads();
  if (tid == 0)
    lossout[0] = ((sred[0] + sred[1]) + (sred[2] + sred[3])) * (1.0f / 4194304.0f);
}

// ---------------- Kernel D: up2 + conv (32->16) + gelu, phase-folded -----------
__device__ __forceinline__ void d1_loadi3(float (&dst)[3][3], const float* t) {
#pragma unroll
  for (int dy = 0; dy < 3; ++dy)
#pragma unroll
    for (int dx = 0; dx < 3; ++dx) dst[dy][dx] = t[dy * 20 + dx];
}
__device__ __forceinline__ void d1_fma(float (&acc)[4][8], const float (&i3)[3][3],
                                       const float* wp) {
#pragma unroll
  for (int p = 0; p < 4; ++p) {
    int a = p >> 1, b2 = p & 1;
#pragma unroll
    for (int tp = 0; tp < 4; ++tp) {
      int dy = tp >> 1, dx = tp & 1;
      float iv = i3[a + dy][b2 + dx];
#pragma unroll
      for (int o2 = 0; o2 < 8; ++o2)
        acc[p][o2] = fmaf(iv, wp[(p * 4 + tp) * 8 + o2], acc[p][o2]);
    }
  }
}
__global__ __launch_bounds__(256) void k_dec1(const float* __restrict__ q,
                                              const float* __restrict__ fwd1,
                                              const float* __restrict__ bias,
                                              float* __restrict__ o) {
  __shared__ float st[32 * 200];  // [ic][10 rows][20]
  int tid = threadIdx.x;
  int b = blockIdx.y;
  int R0 = (blockIdx.x >> 2) * 8, C0 = (blockIdx.x & 3) * 16;
  const float* ip = q + (size_t)b * 131072;
  for (int i = tid; i < 5760; i += 256) {  // 32 ic x 10 x 18
    int ic = i / 180, rr = (i % 180) / 18, cc = i % 18;
    int r = R0 - 1 + rr, c = C0 - 1 + cc;
    st[ic * 200 + rr * 20 + cc] =
        ((unsigned)r < 64u && (unsigned)c < 64u) ? ip[ic * 4096 + r * 64 + c] : 0.f;
  }
  __syncthreads();
  int lane = tid & 63, wid = tid >> 6;
  int qx = wid & 1;
  int grp = __builtin_amdgcn_readfirstlane(wid >> 1);
  int ty = lane >> 3, tx = qx * 8 + (lane & 7);
  float acc[4][8];
#pragma unroll
  for (int p = 0; p < 4; ++p)
#pragma unroll
    for (int o2 = 0; o2 < 8; ++o2) acc[p][o2] = 0.f;
  const float* wb = fwd1 + grp * 4096;
  const float* tb = st + ty * 20 + tx;
  float i3A[3][3], i3B[3][3];
  d1_loadi3(i3A, tb);
#pragma unroll 1
  for (int ic = 0; ic < 32; ic += 2) {
    d1_loadi3(i3B, tb + (ic + 1) * 200);
    d1_fma(acc, i3A, wb + ic * 128);
    d1_loadi3(i3A, tb + ((ic + 2) & 31) * 200);  // wrap: harmless re-read
    d1_fma(acc, i3B, wb + (ic + 1) * 128);
  }
  int Y = 2 * (R0 + ty), X = 2 * (C0 + tx);
#pragma unroll
  for (int o2 = 0; o2 < 8; ++o2) {
    int oc = grp * 8 + o2;
    float bb = bias[oc];
    float* p = o + (size_t)b * 262144 + (size_t)oc * 16384 + Y * 128 + X;
    float2 r0v, r1v;
    r0v.x = GELU(acc[0][o2] + bb);
    r0v.y = GELU(acc[1][o2] + bb);
    r1v.x = GELU(acc[2][o2] + bb);
    r1v.y = GELU(acc[3][o2] + bb);
    *(float2*)p = r0v;
    *(float2*)(p + 128) = r1v;
  }
}

// ---------------- Kernel E: up2 + conv (16->1) + clip, phase-folded ------------
__global__ __launch_bounds__(256) void k_dec2(const float* __restrict__ d1,
                                              const float* __restrict__ fwd2,
                                              const float* __restrict__ bias,
                                              float* __restrict__ out) {
  __shared__ float st[16 * 360];  // [ic][18 rows][20]
  int tid = threadIdx.x;
  int b = blockIdx.y;
  int R0 = (blockIdx.x >> 3) * 16, C0 = (blockIdx.x & 7) * 16;
  const float* ip = d1 + (size_t)b * 262144;
  for (int i = tid; i < 5184; i += 256) {  // 16 ic x 18 x 18
    int ic = i / 324, rr = (i % 324) / 18, cc = i % 18;
    int r = R0 - 1 + rr, c = C0 - 1 + cc;
    st[ic * 360 + rr * 20 + cc] =
        ((unsigned)r < 128u && (unsigned)c < 128u) ? ip[ic * 16384 + r * 128 + c] : 0.f;
  }
  __syncthreads();
  int lane = tid & 63, wid = tid >> 6;
  int qy = wid >> 1, qx = wid & 1;
  int ty = qy * 8 + (lane >> 3), tx = qx * 8 + (lane & 7);
  float acc[4] = {0.f, 0.f, 0.f, 0.f};
#pragma unroll 1
  for (int ic = 0; ic < 16; ++ic) {
    const float* t = st + ic * 360 + ty * 20 + tx;
    float i3[3][3];
#pragma unroll
    for (int dy = 0; dy < 3; ++dy)
#pragma unroll
      for (int dx = 0; dx < 3; ++dx) i3[dy][dx] = t[dy * 20 + dx];
    const float* wp = fwd2 + ic * 16;  // scalar loads
#pragma unroll
    for (int p = 0; p < 4; ++p) {
      int a = p >> 1, b2 = p & 1;
#pragma unroll
      for (int tp = 0; tp < 4; ++tp) {
        int dy = tp >> 1, dx = tp & 1;
        acc[p] = fmaf(i3[a + dy][b2 + dx], wp[p * 4 + tp], acc[p]);
      }
    }
  }
  float bv = bias[0];
  int Y = 2 * (R0 + ty), X = 2 * (C0 + tx);
  float* op = out + (size_t)b * 65536 + Y * 256 + X;
  float2 r0v, r1v;
  r0v.x = fminf(1.0f, fmaxf(-1.0f, acc[0] + bv));
  r0v.y = fminf(1.0f, fmaxf(-1.0f, acc[1] + bv));
  r1v.x = fminf(1.0f, fmaxf(-1.0f, acc[2] + bv));
  r1v.y = fminf(1.0f, fmaxf(-1.0f, acc[3] + bv));
  *(float2*)op = r0v;
  *(float2*)(op + 256) = r1v;
}

extern "C" void kernel_launch(void* const* d_in, const int* in_sizes, int n_in,
                              void* d_out, int out_size, void* d_ws, size_t ws_size,
                              hipStream_t stream) {
  const float* x   = (const float*)d_in[0];
  const float* e1w = (const float*)d_in[1];
  const float* e1b = (const float*)d_in[2];
  const float* e2w = (const float*)d_in[3];
  const float* e2b = (const float*)d_in[4];
  const float* cb  = (const float*)d_in[5];
  const float* d1w = (const float*)d_in[6];
  const float* d1b = (const float*)d_in[7];
  const float* d2w = (const float*)d_in[8];
  const float* d2b = (const float*)d_in[9];

  float* out = (float*)d_out;
  float* y       = out;                       // [32,1,256,256] = 2097152
  float* idxout  = out + 2097152;             // [32,64,64]     = 131072 (as float)
  float* lossout = out + 2097152 + 131072;    // scalar

  float* ws = (float*)d_ws;
  float* h1      = ws;                        // [32,16,128,128] = 8388608 floats
  float* h2      = ws + 8388608;              // [32,32,64,64]   = 4194304 floats
  float* partial = ws + 12582912;             // 512 floats
  float* fwe2    = ws + 12583424;             // 4608
  float* fwd1    = ws + 12588032;             // 8192
  float* fwd2    = ws + 12596224;             // 256
  // VQ chunk outputs reuse the (dead-after-enc2) h1 region:
  float* dists   = ws;                        // 4 x 131072 floats
  int*   idxs    = (int*)(ws + 524288);       // 4 x 131072 ints
  float* d1o     = h1;                        // dec1 output reuses h1 (after merge)

  k_fold<<<dim3(51), 256, 0, stream>>>(e2w, d1w, d2w, fwe2, fwd1, fwd2);
  k_enc1<<<dim3(2048), 256, 0, stream>>>(x, e1w, e1b, h1);
  k_enc2<<<dim3(64, 32), 256, 0, stream>>>(h1, fwe2, e2b, h2);
  k_vq_chunk<<<dim3(1024), 256, 0, stream>>>(h2, cb, dists, idxs);
  k_vq_merge<<<dim3(512), 256, 0, stream>>>(h2, cb, dists, idxs, idxout, partial);
  k_loss<<<dim3(1), 256, 0, stream>>>(partial, lossout);
  k_dec1<<<dim3(32, 32), 256, 0, stream>>>(h2, fwd1, d1b, d1o);
  k_dec2<<<dim3(64, 32), 256, 0, stream>>>(d1o, fwd2, d2b, y);
}

// Round 8
// 288.477 us; speedup vs baseline: 1.2442x; 1.2442x over previous
//
#include <hip/hip_runtime.h>
#include <math.h>

#define GELU(v) (0.5f * (v) * (1.0f + erff((v)*0.70710678118654752440f)))

typedef __attribute__((ext_vector_type(8))) short short8;
typedef __attribute__((ext_vector_type(4))) float f32x4;
#define MFMA16 __builtin_amdgcn_mfma_f32_16x16x32_bf16

// Exact 3-way bf16 split of fp32 (24 = 3x8 mantissa bits, truncation):
// v == p1 + p2 + p3 exactly (each pi representable in bf16).
#define SPLIT3(V, U1, U2, U3)                                                  \
  unsigned U1 = __float_as_uint(V) & 0xFFFF0000u;                              \
  float _r1 = (V)-__uint_as_float(U1);                                         \
  unsigned U2 = __float_as_uint(_r1) & 0xFFFF0000u;                            \
  float _r2 = _r1 - __uint_as_float(U2);                                       \
  unsigned U3 = __float_as_uint(_r2) & 0xFFFF0000u;

// ---------------- Setup: fold weights + split codebook + csq -------------------
// fwe2[grp(4)][ic(16)][k(9)][o(8)]            : enc2 transposed    (4608)
// fwd1[grp(2)][ic(32)][phase(4)][tap(4)][o(8)]: dec1 up2-folded    (8192)
// fwd2[ic(16)][phase(4)][tap(4)]              : dec2 up2-folded    (256)
// cbs[part(3)][code(512)][ch(32)] bf16        : codebook 3-way split
// csqg[512]                                   : ||c||^2
__global__ __launch_bounds__(256) void k_fold(const float* __restrict__ e2w,
                                              const float* __restrict__ d1w,
                                              const float* __restrict__ d2w,
                                              const float* __restrict__ cb,
                                              float* __restrict__ fwe2,
                                              float* __restrict__ fwd1,
                                              float* __restrict__ fwd2,
                                              unsigned short* __restrict__ cbs,
                                              float* __restrict__ csqg) {
  int i = blockIdx.x * 256 + threadIdx.x;
  if (i < 4608) {
    int o = i & 7, k = (i >> 3) % 9, ic = (i / 72) & 15, grp = i / 1152;
    fwe2[i] = e2w[((grp * 8 + o) * 16 + ic) * 9 + k];
  } else if (i < 12800) {
    int j = i - 4608;
    int o = j & 7, pt = (j >> 3) & 15, ic = (j >> 7) & 31, grp = j >> 12;
    int a = pt >> 3, b2 = (pt >> 2) & 1, dy = (pt >> 1) & 1, dx = pt & 1;
    const float* wsrc = d1w + ((grp * 8 + o) * 32 + ic) * 9;
    float s = 0.f;
    for (int ky = 0; ky < 3; ++ky) {
      int rm = (a == 0) ? (ky == 0 ? 0 : 1) : (ky == 2 ? 1 : 0);
      if (rm != dy) continue;
      for (int kx = 0; kx < 3; ++kx) {
        int cm = (b2 == 0) ? (kx == 0 ? 0 : 1) : (kx == 2 ? 1 : 0);
        if (cm == dx) s += wsrc[ky * 3 + kx];
      }
    }
    fwd1[j] = s;
  } else if (i < 13056) {
    int j = i - 12800;
    int pt = j & 15, ic = j >> 4;
    int a = pt >> 3, b2 = (pt >> 2) & 1, dy = (pt >> 1) & 1, dx = pt & 1;
    const float* wsrc = d2w + ic * 9;
    float s = 0.f;
    for (int ky = 0; ky < 3; ++ky) {
      int rm = (a == 0) ? (ky == 0 ? 0 : 1) : (ky == 2 ? 1 : 0);
      if (rm != dy) continue;
      for (int kx = 0; kx < 3; ++kx) {
        int cm = (b2 == 0) ? (kx == 0 ? 0 : 1) : (kx == 2 ? 1 : 0);
        if (cm == dx) s += wsrc[ky * 3 + kx];
      }
    }
    fwd2[j] = s;
  } else if (i < 29440) {
    int j = i - 13056;  // [0, 16384): code = j>>5, ch = j&31
    float v = cb[j];
    SPLIT3(v, u1, u2, u3)
    cbs[j] = (unsigned short)(u1 >> 16);
    cbs[16384 + j] = (unsigned short)(u2 >> 16);
    cbs[32768 + j] = (unsigned short)(u3 >> 16);
  } else if (i < 29952) {
    int c = i - 29440;
    const float* row = cb + (size_t)c * 32;
    float s = 0.f;
#pragma unroll
    for (int d = 0; d < 32; ++d) s = fmaf(row[d], row[d], s);
    csqg[c] = s;
  }
}

// ---------------- Kernel A: conv1 (1->16) + maxpool2 + gelu --------------------
__global__ __launch_bounds__(256) void k_enc1(const float* __restrict__ x,
                                              const float* __restrict__ w,
                                              const float* __restrict__ bias,
                                              float* __restrict__ h1) {
  int gid = blockIdx.x * 256 + threadIdx.x;
  int xx = gid & 127, yy = (gid >> 7) & 127, b = gid >> 14;
  const float* xp = x + (size_t)b * 65536;
  int r0 = 2 * yy - 1, c0 = 2 * xx - 1;
  float in[4][4];
#pragma unroll
  for (int i = 0; i < 4; ++i) {
    int r = r0 + i;
    bool rv = (unsigned)r < 256u;
#pragma unroll
    for (int j = 0; j < 4; ++j) {
      int c = c0 + j;
      in[i][j] = (rv && (unsigned)c < 256u) ? xp[r * 256 + c] : 0.0f;
    }
  }
  float* op = h1 + (size_t)b * 262144 + yy * 128 + xx;
#pragma unroll
  for (int oc = 0; oc < 16; ++oc) {
    const float* wp = w + oc * 9;  // uniform -> s_load
    float s00 = 0.f, s01 = 0.f, s10 = 0.f, s11 = 0.f;
#pragma unroll
    for (int ky = 0; ky < 3; ++ky)
#pragma unroll
      for (int kx = 0; kx < 3; ++kx) {
        float wv = wp[ky * 3 + kx];
        s00 = fmaf(in[ky][kx], wv, s00);
        s01 = fmaf(in[ky][kx + 1], wv, s01);
        s10 = fmaf(in[ky + 1][kx], wv, s10);
        s11 = fmaf(in[ky + 1][kx + 1], wv, s11);
      }
    float m = fmaxf(fmaxf(s00, s01), fmaxf(s10, s11)) + bias[oc];
    op[oc * 16384] = GELU(m);
  }
}

// ---------------- Kernel B: conv2 (16->32) + maxpool2 --------------------------
__device__ __forceinline__ void e2_loadiv(float (&dst)[4][4], const float* t) {
#pragma unroll
  for (int dy = 0; dy < 4; ++dy)
#pragma unroll
    for (int dx = 0; dx < 4; ++dx)
      dst[dy][dx] = t[dy * 20 + (dx & 1) * 10 + (dx >> 1)];
}
__device__ __forceinline__ void e2_fma(float (&acc)[4][8], const float (&iv)[4][4],
                                       const float* wp) {
#pragma unroll
  for (int k = 0; k < 9; ++k) {
    int ky = k / 3, kx = k % 3;
#pragma unroll
    for (int o = 0; o < 8; ++o) {
      float wv = wp[k * 8 + o];
      acc[0][o] = fmaf(iv[ky][kx], wv, acc[0][o]);
      acc[1][o] = fmaf(iv[ky][kx + 1], wv, acc[1][o]);
      acc[2][o] = fmaf(iv[ky + 1][kx], wv, acc[2][o]);
      acc[3][o] = fmaf(iv[ky + 1][kx + 1], wv, acc[3][o]);
    }
  }
}
__global__ __launch_bounds__(256) void k_enc2(const float* __restrict__ h1,
                                              const float* __restrict__ fwe2,
                                              const float* __restrict__ bias,
                                              float* __restrict__ h2) {
  __shared__ float st[16 * 360];  // [ic][18 rows][20: evens 0-9, odds 10-19]
  int tid = threadIdx.x;
  int b = blockIdx.y;
  int Y0 = (blockIdx.x >> 3) * 8, X0 = (blockIdx.x & 7) * 8;
  int r_s = 2 * Y0 - 1, c_s = 2 * X0 - 1;
  const float* ip = h1 + (size_t)b * 262144;
  for (int i = tid; i < 5184; i += 256) {  // 16 ic x 18 x 18
    int ic = i / 324, rr = (i % 324) / 18, cc = i % 18;
    int r = r_s + rr, c = c_s + cc;
    float v = ((unsigned)r < 128u && (unsigned)c < 128u) ? ip[ic * 16384 + r * 128 + c] : 0.f;
    st[ic * 360 + rr * 20 + (cc & 1) * 10 + (cc >> 1)] = v;
  }
  __syncthreads();
  int lane = tid & 63;
  int grp = __builtin_amdgcn_readfirstlane(tid >> 6);
  int oc0 = grp * 8;
  int ty = lane >> 3, tx = lane & 7;
  float acc[4][8];
#pragma unroll
  for (int p = 0; p < 4; ++p)
#pragma unroll
    for (int o = 0; o < 8; ++o) acc[p][o] = 0.f;
  const float* wgrp = fwe2 + grp * 1152;  // scalar base
  const float* tb = st + (2 * ty) * 20 + tx;
  float ivA[4][4], ivB[4][4];
  e2_loadiv(ivA, tb);
#pragma unroll 1
  for (int ic = 0; ic < 16; ic += 2) {
    e2_loadiv(ivB, tb + (ic + 1) * 360);
    e2_fma(acc, ivA, wgrp + ic * 72);
    e2_loadiv(ivA, tb + ((ic + 2) & 15) * 360);  // wrap: harmless re-read
    e2_fma(acc, ivB, wgrp + (ic + 1) * 72);
  }
  float* op = h2 + (size_t)b * 131072 + (Y0 + ty) * 64 + X0 + tx;
#pragma unroll
  for (int o = 0; o < 8; ++o) {
    float m = fmaxf(fmaxf(acc[0][o], acc[1][o]), fmaxf(acc[2][o], acc[3][o])) + bias[oc0 + o];
    op[(oc0 + o) * 4096] = m;
  }
}

// ---------------- Kernel C: VQ via exact-split bf16 MFMA -----------------------
// Block = 256 tokens (4 waves x 64). Tokens split 3-way into LDS (61KB), A-frags
// loaded ONCE into VGPRs (48 regs) -> reused across all 512 codes. Codebook
// pre-split in global bf16 (cbs); B-frags streamed per-lane-divergent (16B/lane,
// real bandwidth, in-order vmcnt, A/B ping-pong). Score S = f.c via 6 chained
// MFMAs (f1c1,f1c2,f2c1,f2c2,f1c3,f3c1): error ~2^-24 rel = fp32-class, so
// argmin matches the fp32 path. Epilogue: d = csq - 2*S in fp32, per-col running
// best, shfl_xor lexicographic merge (r4-tested), quantize+idx+loss fused.
// MFMA layouts (m89-verified): A lane: row=l&15, k=(l>>4)*8+j; B lane: col=l&15,
// same k; D: col=l&15, row=(l>>4)*4+reg.
__global__ __launch_bounds__(256) void k_vq(float* __restrict__ h2,
                                            const float* __restrict__ cb,
                                            const unsigned short* __restrict__ cbs,
                                            const float* __restrict__ csqg,
                                            float* __restrict__ idxout,
                                            float* __restrict__ partial) {
  __shared__ unsigned short sA[3 * 256 * 40];  // [part][tok][40: ch 0-31 + pad]
  __shared__ float sred[4];
  int tid = threadIdx.x;
  int blk = blockIdx.x;
  int t0 = blk * 256;
  size_t abase = (size_t)(t0 >> 12) * 131072 + (t0 & 4095);

  // ---- stage + split tokens (thread = token, 32 ch) ----
  {
    const float* src = h2 + abase + tid;
#pragma unroll
    for (int ch = 0; ch < 32; ++ch) {
      float v = src[ch * 4096];
      SPLIT3(v, u1, u2, u3)
      sA[(0 * 256 + tid) * 40 + ch] = (unsigned short)(u1 >> 16);
      sA[(1 * 256 + tid) * 40 + ch] = (unsigned short)(u2 >> 16);
      sA[(2 * 256 + tid) * 40 + ch] = (unsigned short)(u3 >> 16);
    }
  }
  __syncthreads();

  int l = tid & 63, w = tid >> 6;
  int cl = l & 15, k0 = (l >> 4) * 8;
  // ---- A-frags: 3 parts x 4 token-quads, loaded once ----
  short8 af[3][4];
#pragma unroll
  for (int p = 0; p < 3; ++p)
#pragma unroll
    for (int tq = 0; tq < 4; ++tq) {
      int tok = w * 64 + tq * 16 + cl;
      af[p][tq] = *(const short8*)(sA + (p * 256 + tok) * 40 + k0);
    }

  float bd[4][4];
  int bi[4][4];
#pragma unroll
  for (int a = 0; a < 4; ++a)
#pragma unroll
    for (int b = 0; b < 4; ++b) { bd[a][b] = 3.4e38f; bi[a][b] = 0; }

#define LOADB(S, CT)                                                           \
  {                                                                            \
    int col = (CT)*16 + cl;                                                    \
    b1##S = *(const short8*)(cbs + (0 * 512 + col) * 32 + k0);                 \
    b2##S = *(const short8*)(cbs + (1 * 512 + col) * 32 + k0);                 \
    b3##S = *(const short8*)(cbs + (2 * 512 + col) * 32 + k0);                 \
    cq##S = csqg[col];                                                         \
  }
#define COMPUTE(S, CT)                                                         \
  {                                                                            \
    _Pragma("unroll") for (int tq = 0; tq < 4; ++tq) {                         \
      f32x4 acc = {0.f, 0.f, 0.f, 0.f};                                        \
      acc = MFMA16(af[0][tq], b1##S, acc, 0, 0, 0);                            \
      acc = MFMA16(af[0][tq], b2##S, acc, 0, 0, 0);                            \
      acc = MFMA16(af[1][tq], b1##S, acc, 0, 0, 0);                            \
      acc = MFMA16(af[1][tq], b2##S, acc, 0, 0, 0);                            \
      acc = MFMA16(af[0][tq], b3##S, acc, 0, 0, 0);                            \
      acc = MFMA16(af[2][tq], b1##S, acc, 0, 0, 0);                            \
      _Pragma("unroll") for (int i = 0; i < 4; ++i) {                          \
        float d = fmaf(-2.f, acc[i], cq##S);                                   \
        if (d < bd[tq][i]) { bd[tq][i] = d; bi[tq][i] = (CT)*16 + cl; }        \
      }                                                                        \
    }                                                                          \
  }

  short8 b1A, b2A, b3A, b1B, b2B, b3B;
  float cqA, cqB;
  LOADB(A, 0)
#pragma unroll 1
  for (int ct = 0; ct < 32; ct += 2) {
    LOADB(B, ct + 1)
    COMPUTE(A, ct)
    LOADB(A, (ct + 2) & 31)  // wrap: in-bounds, unused on last iter
    COMPUTE(B, ct + 1)
  }
#undef LOADB
#undef COMPUTE

  // ---- cross-lane argmin over 16 cols (lanes stride 1 in low 4 bits) ----
#pragma unroll
  for (int tq = 0; tq < 4; ++tq)
#pragma unroll
    for (int i = 0; i < 4; ++i)
#pragma unroll
      for (int m = 1; m < 16; m <<= 1) {
        float od = __shfl_xor(bd[tq][i], m, 64);
        int ob = __shfl_xor(bi[tq][i], m, 64);
        if (od < bd[tq][i] || (od == bd[tq][i] && ob < bi[tq][i])) {
          bd[tq][i] = od;
          bi[tq][i] = ob;
        }
      }

  // ---- epilogue: writer lanes (cl<4) quantize token row (l>>4)*4+cl ----
  float loss = 0.f;
  if (cl < 4) {
#pragma unroll
    for (int tq = 0; tq < 4; ++tq) {
      int bv = bi[tq][0];  // static-index select (rule #20)
      bv = (cl == 1) ? bi[tq][1] : bv;
      bv = (cl == 2) ? bi[tq][2] : bv;
      bv = (cl == 3) ? bi[tq][3] : bv;
      int tokl = w * 64 + tq * 16 + (l >> 4) * 4 + cl;
      idxout[t0 + tokl] = (float)bv;
      const float* q = cb + (size_t)bv * 32;
      float* hp = h2 + abase + tokl;
      float lss = 0.f;
#pragma unroll
      for (int ch = 0; ch < 32; ++ch) {
        float fv = hp[ch * 4096];
        float qv = q[ch];
        float dd = qv - fv;
        lss = fmaf(dd, dd, lss);
        hp[ch * 4096] = qv;
      }
      loss += lss;
    }
  }
#pragma unroll
  for (int off = 32; off > 0; off >>= 1) loss += __shfl_down(loss, off, 64);
  if (l == 0) sred[w] = loss;
  __syncthreads();
  if (tid == 0) partial[blk] = (sred[0] + sred[1]) + (sred[2] + sred[3]);
}

// ---------------- Kernel F: finalize commit loss (512 partials) ----------------
__global__ __launch_bounds__(256) void k_loss(const float* __restrict__ partial,
                                              float* __restrict__ lossout) {
  __shared__ float sred[4];
  int tid = threadIdx.x;
  float v = partial[tid] + partial[tid + 256];
#pragma unroll
  for (int off = 32; off > 0; off >>= 1) v += __shfl_down(v, off, 64);
  if ((tid & 63) == 0) sred[tid >> 6] = v;
  __syncthreads();
  if (tid == 0)
    lossout[0] = ((sred[0] + sred[1]) + (sred[2] + sred[3])) * (1.0f / 4194304.0f);
}

// ---------------- Kernel D: up2 + conv (32->16) + gelu, phase-folded -----------
__device__ __forceinline__ void d1_loadi3(float (&dst)[3][3], const float* t) {
#pragma unroll
  for (int dy = 0; dy < 3; ++dy)
#pragma unroll
    for (int dx = 0; dx < 3; ++dx) dst[dy][dx] = t[dy * 20 + dx];
}
__device__ __forceinline__ void d1_fma(float (&acc)[4][8], const float (&i3)[3][3],
                                       const float* wp) {
#pragma unroll
  for (int p = 0; p < 4; ++p) {
    int a = p >> 1, b2 = p & 1;
#pragma unroll
    for (int tp = 0; tp < 4; ++tp) {
      int dy = tp >> 1, dx = tp & 1;
      float iv = i3[a + dy][b2 + dx];
#pragma unroll
      for (int o2 = 0; o2 < 8; ++o2)
        acc[p][o2] = fmaf(iv, wp[(p * 4 + tp) * 8 + o2], acc[p][o2]);
    }
  }
}
__global__ __launch_bounds__(256) void k_dec1(const float* __restrict__ q,
                                              const float* __restrict__ fwd1,
                                              const float* __restrict__ bias,
                                              float* __restrict__ o) {
  __shared__ float st[32 * 200];  // [ic][10 rows][20]
  int tid = threadIdx.x;
  int b = blockIdx.y;
  int R0 = (blockIdx.x >> 2) * 8, C0 = (blockIdx.x & 3) * 16;
  const float* ip = q + (size_t)b * 131072;
  for (int i = tid; i < 5760; i += 256) {  // 32 ic x 10 x 18
    int ic = i / 180, rr = (i % 180) / 18, cc = i % 18;
    int r = R0 - 1 + rr, c = C0 - 1 + cc;
    st[ic * 200 + rr * 20 + cc] =
        ((unsigned)r < 64u && (unsigned)c < 64u) ? ip[ic * 4096 + r * 64 + c] : 0.f;
  }
  __syncthreads();
  int lane = tid & 63, wid = tid >> 6;
  int qx = wid & 1;
  int grp = __builtin_amdgcn_readfirstlane(wid >> 1);
  int ty = lane >> 3, tx = qx * 8 + (lane & 7);
  float acc[4][8];
#pragma unroll
  for (int p = 0; p < 4; ++p)
#pragma unroll
    for (int o2 = 0; o2 < 8; ++o2) acc[p][o2] = 0.f;
  const float* wb = fwd1 + grp * 4096;
  const float* tb = st + ty * 20 + tx;
  float i3A[3][3], i3B[3][3];
  d1_loadi3(i3A, tb);
#pragma unroll 1
  for (int ic = 0; ic < 32; ic += 2) {
    d1_loadi3(i3B, tb + (ic + 1) * 200);
    d1_fma(acc, i3A, wb + ic * 128);
    d1_loadi3(i3A, tb + ((ic + 2) & 31) * 200);  // wrap: harmless re-read
    d1_fma(acc, i3B, wb + (ic + 1) * 128);
  }
  int Y = 2 * (R0 + ty), X = 2 * (C0 + tx);
#pragma unroll
  for (int o2 = 0; o2 < 8; ++o2) {
    int oc = grp * 8 + o2;
    float bb = bias[oc];
    float* p = o + (size_t)b * 262144 + (size_t)oc * 16384 + Y * 128 + X;
    float2 r0v, r1v;
    r0v.x = GELU(acc[0][o2] + bb);
    r0v.y = GELU(acc[1][o2] + bb);
    r1v.x = GELU(acc[2][o2] + bb);
    r1v.y = GELU(acc[3][o2] + bb);
    *(float2*)p = r0v;
    *(float2*)(p + 128) = r1v;
  }
}

// ---------------- Kernel E: up2 + conv (16->1) + clip, phase-folded ------------
__global__ __launch_bounds__(256) void k_dec2(const float* __restrict__ d1,
                                              const float* __restrict__ fwd2,
                                              const float* __restrict__ bias,
                                              float* __restrict__ out) {
  __shared__ float st[16 * 360];  // [ic][18 rows][20]
  int tid = threadIdx.x;
  int b = blockIdx.y;
  int R0 = (blockIdx.x >> 3) * 16, C0 = (blockIdx.x & 7) * 16;
  const float* ip = d1 + (size_t)b * 262144;
  for (int i = tid; i < 5184; i += 256) {  // 16 ic x 18 x 18
    int ic = i / 324, rr = (i % 324) / 18, cc = i % 18;
    int r = R0 - 1 + rr, c = C0 - 1 + cc;
    st[ic * 360 + rr * 20 + cc] =
        ((unsigned)r < 128u && (unsigned)c < 128u) ? ip[ic * 16384 + r * 128 + c] : 0.f;
  }
  __syncthreads();
  int lane = tid & 63, wid = tid >> 6;
  int qy = wid >> 1, qx = wid & 1;
  int ty = qy * 8 + (lane >> 3), tx = qx * 8 + (lane & 7);
  float acc[4] = {0.f, 0.f, 0.f, 0.f};
#pragma unroll 1
  for (int ic = 0; ic < 16; ++ic) {
    const float* t = st + ic * 360 + ty * 20 + tx;
    float i3[3][3];
#pragma unroll
    for (int dy = 0; dy < 3; ++dy)
#pragma unroll
      for (int dx = 0; dx < 3; ++dx) i3[dy][dx] = t[dy * 20 + dx];
    const float* wp = fwd2 + ic * 16;  // scalar loads
#pragma unroll
    for (int p = 0; p < 4; ++p) {
      int a = p >> 1, b2 = p & 1;
#pragma unroll
      for (int tp = 0; tp < 4; ++tp) {
        int dy = tp >> 1, dx = tp & 1;
        acc[p] = fmaf(i3[a + dy][b2 + dx], wp[p * 4 + tp], acc[p]);
      }
    }
  }
  float bv = bias[0];
  int Y = 2 * (R0 + ty), X = 2 * (C0 + tx);
  float* op = out + (size_t)b * 65536 + Y * 256 + X;
  float2 r0v, r1v;
  r0v.x = fminf(1.0f, fmaxf(-1.0f, acc[0] + bv));
  r0v.y = fminf(1.0f, fmaxf(-1.0f, acc[1] + bv));
  r1v.x = fminf(1.0f, fmaxf(-1.0f, acc[2] + bv));
  r1v.y = fminf(1.0f, fmaxf(-1.0f, acc[3] + bv));
  *(float2*)op = r0v;
  *(float2*)(op + 256) = r1v;
}

extern "C" void kernel_launch(void* const* d_in, const int* in_sizes, int n_in,
                              void* d_out, int out_size, void* d_ws, size_t ws_size,
                              hipStream_t stream) {
  const float* x   = (const float*)d_in[0];
  const float* e1w = (const float*)d_in[1];
  const float* e1b = (const float*)d_in[2];
  const float* e2w = (const float*)d_in[3];
  const float* e2b = (const float*)d_in[4];
  const float* cb  = (const float*)d_in[5];
  const float* d1w = (const float*)d_in[6];
  const float* d1b = (const float*)d_in[7];
  const float* d2w = (const float*)d_in[8];
  const float* d2b = (const float*)d_in[9];

  float* out = (float*)d_out;
  float* y       = out;                       // [32,1,256,256] = 2097152
  float* idxout  = out + 2097152;             // [32,64,64]     = 131072 (as float)
  float* lossout = out + 2097152 + 131072;    // scalar

  float* ws = (float*)d_ws;
  float* h1      = ws;                        // [32,16,128,128] = 8388608 floats
  float* h2      = ws + 8388608;              // [32,32,64,64]   = 4194304 floats
  float* partial = ws + 12582912;             // 512 floats
  float* fwe2    = ws + 12583424;             // 4608
  float* fwd1    = ws + 12588032;             // 8192
  float* fwd2    = ws + 12596224;             // 256
  float* d1o     = h1;                        // dec1 output reuses h1 (after vq)

  // cbs (split codebook, 49152 bf16 = 24576 floats) + csqg (512) live in the y
  // region of out: written by k_fold, read by k_vq, fully overwritten by k_dec2.
  unsigned short* cbs = (unsigned short*)out;
  float* csqg = out + 24576;

  k_fold<<<dim3(117), 256, 0, stream>>>(e2w, d1w, d2w, cb, fwe2, fwd1, fwd2, cbs, csqg);
  k_enc1<<<dim3(2048), 256, 0, stream>>>(x, e1w, e1b, h1);
  k_enc2<<<dim3(64, 32), 256, 0, stream>>>(h1, fwe2, e2b, h2);
  k_vq<<<dim3(512), 256, 0, stream>>>(h2, cb, cbs, csqg, idxout, partial);
  k_loss<<<dim3(1), 256, 0, stream>>>(partial, lossout);
  k_dec1<<<dim3(32, 32), 256, 0, stream>>>(h2, fwd1, d1b, d1o);
  k_dec2<<<dim3(64, 32), 256, 0, stream>>>(d1o, fwd2, d2b, y);
}

// Round 9
// 275.103 us; speedup vs baseline: 1.3047x; 1.0486x over previous
//
#include <hip/hip_runtime.h>
#include <math.h>

#define GELU(v) (0.5f * (v) * (1.0f + erff((v)*0.70710678118654752440f)))

typedef __attribute__((ext_vector_type(8))) short short8;
typedef __attribute__((ext_vector_type(4))) float f32x4;
typedef __attribute__((ext_vector_type(16))) float f32x16;
#define MFMA16 __builtin_amdgcn_mfma_f32_16x16x32_bf16
#define MFMA32 __builtin_amdgcn_mfma_f32_32x32x16_bf16

// Exact 3-way bf16 split of fp32 (24 = 3x8 mantissa bits, truncation):
// v == p1 + p2 + p3 exactly (each pi representable in bf16).
#define SPLIT3(V, U1, U2, U3)                                                  \
  unsigned U1 = __float_as_uint(V) & 0xFFFF0000u;                              \
  float _r1 = (V)-__uint_as_float(U1);                                         \
  unsigned U2 = __float_as_uint(_r1) & 0xFFFF0000u;                            \
  float _r2 = _r1 - __uint_as_float(U2);                                       \
  unsigned U3 = __float_as_uint(_r2) & 0xFFFF0000u;

// ---------------- Setup: fold weights + split codebook/enc2-weights ------------
// fwd1[grp(2)][ic(32)][phase(4)][tap(4)][o(8)]: dec1 up2-folded    (8192)
// fwd2[ic(16)][phase(4)][tap(4)]              : dec2 up2-folded    (256)
// cbs[part(3)][code(512)][ch(32)] bf16        : codebook 3-way split
// csqg[512]                                   : ||c||^2
// wfrag[part(3)][tap(9)][lane(64)][j(8)] bf16 : enc2 W B-fragments, lane order
//   frag(p,t,l,j) = part_p( e2w[oc=l&31][ic=(l>>5)*8+j][tap t] )
__global__ __launch_bounds__(256) void k_fold(const float* __restrict__ e2w,
                                              const float* __restrict__ d1w,
                                              const float* __restrict__ d2w,
                                              const float* __restrict__ cb,
                                              float* __restrict__ fwd1,
                                              float* __restrict__ fwd2,
                                              unsigned short* __restrict__ cbs,
                                              float* __restrict__ csqg,
                                              unsigned short* __restrict__ wfrag) {
  int i = blockIdx.x * 256 + threadIdx.x;
  if (i < 8192) {
    int j = i;
    int o = j & 7, pt = (j >> 3) & 15, ic = (j >> 7) & 31, grp = j >> 12;
    int a = pt >> 3, b2 = (pt >> 2) & 1, dy = (pt >> 1) & 1, dx = pt & 1;
    const float* wsrc = d1w + ((grp * 8 + o) * 32 + ic) * 9;
    float s = 0.f;
    for (int ky = 0; ky < 3; ++ky) {
      int rm = (a == 0) ? (ky == 0 ? 0 : 1) : (ky == 2 ? 1 : 0);
      if (rm != dy) continue;
      for (int kx = 0; kx < 3; ++kx) {
        int cm = (b2 == 0) ? (kx == 0 ? 0 : 1) : (kx == 2 ? 1 : 0);
        if (cm == dx) s += wsrc[ky * 3 + kx];
      }
    }
    fwd1[j] = s;
  } else if (i < 8448) {
    int j = i - 8192;
    int pt = j & 15, ic = j >> 4;
    int a = pt >> 3, b2 = (pt >> 2) & 1, dy = (pt >> 1) & 1, dx = pt & 1;
    const float* wsrc = d2w + ic * 9;
    float s = 0.f;
    for (int ky = 0; ky < 3; ++ky) {
      int rm = (a == 0) ? (ky == 0 ? 0 : 1) : (ky == 2 ? 1 : 0);
      if (rm != dy) continue;
      for (int kx = 0; kx < 3; ++kx) {
        int cm = (b2 == 0) ? (kx == 0 ? 0 : 1) : (kx == 2 ? 1 : 0);
        if (cm == dx) s += wsrc[ky * 3 + kx];
      }
    }
    fwd2[j] = s;
  } else if (i < 24832) {
    int j = i - 8448;  // [0, 16384): code = j>>5, ch = j&31
    float v = cb[j];
    SPLIT3(v, u1, u2, u3)
    cbs[j] = (unsigned short)(u1 >> 16);
    cbs[16384 + j] = (unsigned short)(u2 >> 16);
    cbs[32768 + j] = (unsigned short)(u3 >> 16);
  } else if (i < 25344) {
    int c = i - 24832;
    const float* row = cb + (size_t)c * 32;
    float s = 0.f;
#pragma unroll
    for (int d = 0; d < 32; ++d) s = fmaf(row[d], row[d], s);
    csqg[c] = s;
  } else if (i < 39168) {
    int j = i - 25344;  // [0, 13824)
    int p = j / 4608, rem = j - p * 4608;
    int t = rem >> 9, l2 = (rem >> 3) & 63, jj = rem & 7;
    float v = e2w[((l2 & 31) * 16 + ((l2 >> 5) * 8 + jj)) * 9 + t];
    SPLIT3(v, u1, u2, u3)
    unsigned short r = (p == 0)   ? (unsigned short)(u1 >> 16)
                       : (p == 1) ? (unsigned short)(u2 >> 16)
                                  : (unsigned short)(u3 >> 16);
    wfrag[j] = r;
  }
}

// ---------------- Kernel A: conv1 (1->16) + maxpool2 + gelu --------------------
// Output layout CHANGED to h1t[b][y][x][ic16] (ic contiguous) for enc2's MFMA
// staging. Side benefit: per-thread stores become 64B contiguous (were 16 x
// 64KB-strided scalar scatters).
__global__ __launch_bounds__(256) void k_enc1(const float* __restrict__ x,
                                              const float* __restrict__ w,
                                              const float* __restrict__ bias,
                                              float* __restrict__ h1) {
  int gid = blockIdx.x * 256 + threadIdx.x;
  int xx = gid & 127, yy = (gid >> 7) & 127, b = gid >> 14;
  const float* xp = x + (size_t)b * 65536;
  int r0 = 2 * yy - 1, c0 = 2 * xx - 1;
  float in[4][4];
#pragma unroll
  for (int i = 0; i < 4; ++i) {
    int r = r0 + i;
    bool rv = (unsigned)r < 256u;
#pragma unroll
    for (int j = 0; j < 4; ++j) {
      int c = c0 + j;
      in[i][j] = (rv && (unsigned)c < 256u) ? xp[r * 256 + c] : 0.0f;
    }
  }
  float vout[16];
#pragma unroll
  for (int oc = 0; oc < 16; ++oc) {
    const float* wp = w + oc * 9;  // uniform -> s_load
    float s00 = 0.f, s01 = 0.f, s10 = 0.f, s11 = 0.f;
#pragma unroll
    for (int ky = 0; ky < 3; ++ky)
#pragma unroll
      for (int kx = 0; kx < 3; ++kx) {
        float wv = wp[ky * 3 + kx];
        s00 = fmaf(in[ky][kx], wv, s00);
        s01 = fmaf(in[ky][kx + 1], wv, s01);
        s10 = fmaf(in[ky + 1][kx], wv, s10);
        s11 = fmaf(in[ky + 1][kx + 1], wv, s11);
      }
    float m = fmaxf(fmaxf(s00, s01), fmaxf(s10, s11)) + bias[oc];
    vout[oc] = GELU(m);
  }
  float* op = h1 + (size_t)b * 262144 + ((size_t)yy * 128 + xx) * 16;
#pragma unroll
  for (int q = 0; q < 4; ++q) {
    float4 vq;
    vq.x = vout[4 * q + 0]; vq.y = vout[4 * q + 1];
    vq.z = vout[4 * q + 2]; vq.w = vout[4 * q + 3];
    *(float4*)(op + 4 * q) = vq;
  }
}

// ---------------- Kernel B: conv2 (16->32) + maxpool2 via split MFMA -----------
// Implicit GEMM: D[pos(32x)][oc(32)] += A[pos][ic16] x W[ic16][oc] per tap,
// mfma_f32_32x32x16_bf16, 6 split terms (a1w1,a1w2,a2w1,a2w2,a1w3,a3w1) -> ~2^-24
// rel error (r8-proven class; idx-exact). Block = 32x x 8y x 32oc; 4 waves =
// 2y rows each (y-pool pairs in-wave); x-pool pairs are D reg-quads (in-lane).
// LDS: split A planes [part3][ich2][y10][x34] of 16B granules -> per-lane
// stride-1-granule ds_read_b128 (conflict-free class). B frags lane-ordered in
// global (wfrag, coalesced 1KB/load, L1-resident). acc split into even/odd-tap
// chains (4 chains/wave) for MFMA dep-latency cover.
__global__ __launch_bounds__(256) void k_enc2(const float* __restrict__ h1,
                                              const unsigned short* __restrict__ wfrag,
                                              const float* __restrict__ bias,
                                              float* __restrict__ h2) {
  __shared__ __align__(16) unsigned short sA[3 * 2 * 10 * 34 * 8];  // 32640 B
  const int PP = 2 * 10 * 34 * 8;  // part-plane stride (shorts)
  int tid = threadIdx.x;
  int b = blockIdx.y;
  int X0 = (blockIdx.x & 3) * 32, Y0 = (blockIdx.x >> 2) * 8;
  const float* ip = h1 + (size_t)b * 262144;
  for (int i = tid; i < 5440; i += 256) {  // 10 y x 34 x x 16 ic
    int yy = i / 544, rem = i % 544, xx = rem >> 4, ic = rem & 15;
    int y = Y0 - 1 + yy, xg = X0 - 1 + xx;
    float v = ((unsigned)y < 128u && (unsigned)xg < 128u)
                  ? ip[((size_t)y * 128 + xg) * 16 + ic] : 0.f;
    SPLIT3(v, u1, u2, u3)
    int si = (((ic >> 3) * 10 + yy) * 34 + xx) * 8 + (ic & 7);
    sA[si] = (unsigned short)(u1 >> 16);
    sA[PP + si] = (unsigned short)(u2 >> 16);
    sA[2 * PP + si] = (unsigned short)(u3 >> 16);
  }
  __syncthreads();

  int l = tid & 63, w = tid >> 6;
  int xl = l & 31, ich = l >> 5;
  f32x16 acc0[2], acc1[2];
#pragma unroll
  for (int s = 0; s < 2; ++s)
#pragma unroll
    for (int r = 0; r < 16; ++r) { acc0[s][r] = 0.f; acc1[s][r] = 0.f; }

#pragma unroll
  for (int t = 0; t < 9; ++t) {
    int dy = t / 3, dx = t % 3;
    int s = t & 1;
    const unsigned short* wb = wfrag + t * 512 + l * 8;  // [p][t][l][8]
    short8 bf1 = *(const short8*)(wb);
    short8 bf2 = *(const short8*)(wb + 4608);
    short8 bf3 = *(const short8*)(wb + 9216);
    int g0 = ((ich * 10) + (2 * w + dy)) * 34 + xl + dx;  // tile ty=0
    const unsigned short* a0p = sA + g0 * 8;
    short8 a01 = *(const short8*)(a0p);
    short8 a02 = *(const short8*)(a0p + PP);
    short8 a03 = *(const short8*)(a0p + 2 * PP);
    const unsigned short* a1p = a0p + 34 * 8;             // tile ty=1 (+1 y row)
    short8 a11 = *(const short8*)(a1p);
    short8 a12 = *(const short8*)(a1p + PP);
    short8 a13 = *(const short8*)(a1p + 2 * PP);
    acc0[s] = MFMA32(a01, bf1, acc0[s], 0, 0, 0);
    acc0[s] = MFMA32(a01, bf2, acc0[s], 0, 0, 0);
    acc0[s] = MFMA32(a02, bf1, acc0[s], 0, 0, 0);
    acc0[s] = MFMA32(a02, bf2, acc0[s], 0, 0, 0);
    acc0[s] = MFMA32(a01, bf3, acc0[s], 0, 0, 0);
    acc0[s] = MFMA32(a03, bf1, acc0[s], 0, 0, 0);
    acc1[s] = MFMA32(a11, bf1, acc1[s], 0, 0, 0);
    acc1[s] = MFMA32(a11, bf2, acc1[s], 0, 0, 0);
    acc1[s] = MFMA32(a12, bf1, acc1[s], 0, 0, 0);
    acc1[s] = MFMA32(a12, bf2, acc1[s], 0, 0, 0);
    acc1[s] = MFMA32(a11, bf3, acc1[s], 0, 0, 0);
    acc1[s] = MFMA32(a13, bf1, acc1[s], 0, 0, 0);
  }

  // epilogue: merge chains, maxpool 2x2 (x-pairs in reg-quads, y-pairs = tiles)
  float bv = bias[l & 31];
  int ypool = (Y0 >> 1) + w;
  float* op = h2 + (size_t)b * 131072 + (size_t)(l & 31) * 4096 + ypool * 64 + (X0 >> 1);
#pragma unroll
  for (int k = 0; k < 8; ++k) {
    float e0 = (acc0[0][2 * k] + acc0[1][2 * k]);
    float o0 = (acc0[0][2 * k + 1] + acc0[1][2 * k + 1]);
    float e1 = (acc1[0][2 * k] + acc1[1][2 * k]);
    float o1 = (acc1[0][2 * k + 1] + acc1[1][2 * k + 1]);
    float m = fmaxf(fmaxf(e0, o0), fmaxf(e1, o1)) + bv;
    int row = ((2 * k) & 3) + 8 * ((2 * k) >> 2) + 4 * ich;  // D-row of reg 2k
    op[row >> 1] = m;
  }
}

// ---------------- Kernel C: VQ via exact-split bf16 MFMA (r8-verified) ---------
__global__ __launch_bounds__(256) void k_vq(float* __restrict__ h2,
                                            const float* __restrict__ cb,
                                            const unsigned short* __restrict__ cbs,
                                            const float* __restrict__ csqg,
                                            float* __restrict__ idxout,
                                            float* __restrict__ partial) {
  __shared__ unsigned short sA[3 * 256 * 40];  // [part][tok][40: ch 0-31 + pad]
  __shared__ float sred[4];
  int tid = threadIdx.x;
  int blk = blockIdx.x;
  int t0 = blk * 256;
  size_t abase = (size_t)(t0 >> 12) * 131072 + (t0 & 4095);

  {
    const float* src = h2 + abase + tid;
#pragma unroll
    for (int ch = 0; ch < 32; ++ch) {
      float v = src[ch * 4096];
      SPLIT3(v, u1, u2, u3)
      sA[(0 * 256 + tid) * 40 + ch] = (unsigned short)(u1 >> 16);
      sA[(1 * 256 + tid) * 40 + ch] = (unsigned short)(u2 >> 16);
      sA[(2 * 256 + tid) * 40 + ch] = (unsigned short)(u3 >> 16);
    }
  }
  __syncthreads();

  int l = tid & 63, w = tid >> 6;
  int cl = l & 15, k0 = (l >> 4) * 8;
  short8 af[3][4];
#pragma unroll
  for (int p = 0; p < 3; ++p)
#pragma unroll
    for (int tq = 0; tq < 4; ++tq) {
      int tok = w * 64 + tq * 16 + cl;
      af[p][tq] = *(const short8*)(sA + (p * 256 + tok) * 40 + k0);
    }

  float bd[4][4];
  int bi[4][4];
#pragma unroll
  for (int a = 0; a < 4; ++a)
#pragma unroll
    for (int b = 0; b < 4; ++b) { bd[a][b] = 3.4e38f; bi[a][b] = 0; }

#define LOADB(S, CT)                                                           \
  {                                                                            \
    int col = (CT)*16 + cl;                                                    \
    b1##S = *(const short8*)(cbs + (0 * 512 + col) * 32 + k0);                 \
    b2##S = *(const short8*)(cbs + (1 * 512 + col) * 32 + k0);                 \
    b3##S = *(const short8*)(cbs + (2 * 512 + col) * 32 + k0);                 \
    cq##S = csqg[col];                                                         \
  }
#define COMPUTE(S, CT)                                                         \
  {                                                                            \
    _Pragma("unroll") for (int tq = 0; tq < 4; ++tq) {                         \
      f32x4 acc = {0.f, 0.f, 0.f, 0.f};                                        \
      acc = MFMA16(af[0][tq], b1##S, acc, 0, 0, 0);                            \
      acc = MFMA16(af[0][tq], b2##S, acc, 0, 0, 0);                            \
      acc = MFMA16(af[1][tq], b1##S, acc, 0, 0, 0);                            \
      acc = MFMA16(af[1][tq], b2##S, acc, 0, 0, 0);                            \
      acc = MFMA16(af[0][tq], b3##S, acc, 0, 0, 0);                            \
      acc = MFMA16(af[2][tq], b1##S, acc, 0, 0, 0);                            \
      _Pragma("unroll") for (int i = 0; i < 4; ++i) {                          \
        float d = fmaf(-2.f, acc[i], cq##S);                                   \
        if (d < bd[tq][i]) { bd[tq][i] = d; bi[tq][i] = (CT)*16 + cl; }        \
      }                                                                        \
    }                                                                          \
  }

  short8 b1A, b2A, b3A, b1B, b2B, b3B;
  float cqA, cqB;
  LOADB(A, 0)
#pragma unroll 1
  for (int ct = 0; ct < 32; ct += 2) {
    LOADB(B, ct + 1)
    COMPUTE(A, ct)
    LOADB(A, (ct + 2) & 31)  // wrap: in-bounds, unused on last iter
    COMPUTE(B, ct + 1)
  }
#undef LOADB
#undef COMPUTE

#pragma unroll
  for (int tq = 0; tq < 4; ++tq)
#pragma unroll
    for (int i = 0; i < 4; ++i)
#pragma unroll
      for (int m = 1; m < 16; m <<= 1) {
        float od = __shfl_xor(bd[tq][i], m, 64);
        int ob = __shfl_xor(bi[tq][i], m, 64);
        if (od < bd[tq][i] || (od == bd[tq][i] && ob < bi[tq][i])) {
          bd[tq][i] = od;
          bi[tq][i] = ob;
        }
      }

  float loss = 0.f;
  if (cl < 4) {
#pragma unroll
    for (int tq = 0; tq < 4; ++tq) {
      int bv = bi[tq][0];  // static-index select (rule #20)
      bv = (cl == 1) ? bi[tq][1] : bv;
      bv = (cl == 2) ? bi[tq][2] : bv;
      bv = (cl == 3) ? bi[tq][3] : bv;
      int tokl = w * 64 + tq * 16 + (l >> 4) * 4 + cl;
      idxout[t0 + tokl] = (float)bv;
      const float* q = cb + (size_t)bv * 32;
      float* hp = h2 + abase + tokl;
      float lss = 0.f;
#pragma unroll
      for (int ch = 0; ch < 32; ++ch) {
        float fv = hp[ch * 4096];
        float qv = q[ch];
        float dd = qv - fv;
        lss = fmaf(dd, dd, lss);
        hp[ch * 4096] = qv;
      }
      loss += lss;
    }
  }
#pragma unroll
  for (int off = 32; off > 0; off >>= 1) loss += __shfl_down(loss, off, 64);
  if (l == 0) sred[w] = loss;
  __syncthreads();
  if (tid == 0) partial[blk] = (sred[0] + sred[1]) + (sred[2] + sred[3]);
}

// ---------------- Kernel F: finalize commit loss (512 partials) ----------------
__global__ __launch_bounds__(256) void k_loss(const float* __restrict__ partial,
                                              float* __restrict__ lossout) {
  __shared__ float sred[4];
  int tid = threadIdx.x;
  float v = partial[tid] + partial[tid + 256];
#pragma unroll
  for (int off = 32; off > 0; off >>= 1) v += __shfl_down(v, off, 64);
  if ((tid & 63) == 0) sred[tid >> 6] = v;
  __syncthreads();
  if (tid == 0)
    lossout[0] = ((sred[0] + sred[1]) + (sred[2] + sred[3])) * (1.0f / 4194304.0f);
}

// ---------------- Kernel D: up2 + conv (32->16) + gelu, phase-folded -----------
__device__ __forceinline__ void d1_loadi3(float (&dst)[3][3], const float* t) {
#pragma unroll
  for (int dy = 0; dy < 3; ++dy)
#pragma unroll
    for (int dx = 0; dx < 3; ++dx) dst[dy][dx] = t[dy * 20 + dx];
}
__device__ __forceinline__ void d1_fma(float (&acc)[4][8], const float (&i3)[3][3],
                                       const float* wp) {
#pragma unroll
  for (int p = 0; p < 4; ++p) {
    int a = p >> 1, b2 = p & 1;
#pragma unroll
    for (int tp = 0; tp < 4; ++tp) {
      int dy = tp >> 1, dx = tp & 1;
      float iv = i3[a + dy][b2 + dx];
#pragma unroll
      for (int o2 = 0; o2 < 8; ++o2)
        acc[p][o2] = fmaf(iv, wp[(p * 4 + tp) * 8 + o2], acc[p][o2]);
    }
  }
}
__global__ __launch_bounds__(256) void k_dec1(const float* __restrict__ q,
                                              const float* __restrict__ fwd1,
                                              const float* __restrict__ bias,
                                              float* __restrict__ o) {
  __shared__ float st[32 * 200];  // [ic][10 rows][20]
  int tid = threadIdx.x;
  int b = blockIdx.y;
  int R0 = (blockIdx.x >> 2) * 8, C0 = (blockIdx.x & 3) * 16;
  const float* ip = q + (size_t)b * 131072;
  for (int i = tid; i < 5760; i += 256) {  // 32 ic x 10 x 18
    int ic = i / 180, rr = (i % 180) / 18, cc = i % 18;
    int r = R0 - 1 + rr, c = C0 - 1 + cc;
    st[ic * 200 + rr * 20 + cc] =
        ((unsigned)r < 64u && (unsigned)c < 64u) ? ip[ic * 4096 + r * 64 + c] : 0.f;
  }
  __syncthreads();
  int lane = tid & 63, wid = tid >> 6;
  int qx = wid & 1;
  int grp = __builtin_amdgcn_readfirstlane(wid >> 1);
  int ty = lane >> 3, tx = qx * 8 + (lane & 7);
  float acc[4][8];
#pragma unroll
  for (int p = 0; p < 4; ++p)
#pragma unroll
    for (int o2 = 0; o2 < 8; ++o2) acc[p][o2] = 0.f;
  const float* wb = fwd1 + grp * 4096;
  const float* tb = st + ty * 20 + tx;
  float i3A[3][3], i3B[3][3];
  d1_loadi3(i3A, tb);
#pragma unroll 1
  for (int ic = 0; ic < 32; ic += 2) {
    d1_loadi3(i3B, tb + (ic + 1) * 200);
    d1_fma(acc, i3A, wb + ic * 128);
    d1_loadi3(i3A, tb + ((ic + 2) & 31) * 200);  // wrap: harmless re-read
    d1_fma(acc, i3B, wb + (ic + 1) * 128);
  }
  int Y = 2 * (R0 + ty), X = 2 * (C0 + tx);
#pragma unroll
  for (int o2 = 0; o2 < 8; ++o2) {
    int oc = grp * 8 + o2;
    float bb = bias[oc];
    float* p = o + (size_t)b * 262144 + (size_t)oc * 16384 + Y * 128 + X;
    float2 r0v, r1v;
    r0v.x = GELU(acc[0][o2] + bb);
    r0v.y = GELU(acc[1][o2] + bb);
    r1v.x = GELU(acc[2][o2] + bb);
    r1v.y = GELU(acc[3][o2] + bb);
    *(float2*)p = r0v;
    *(float2*)(p + 128) = r1v;
  }
}

// ---------------- Kernel E: up2 + conv (16->1) + clip, phase-folded ------------
__global__ __launch_bounds__(256) void k_dec2(const float* __restrict__ d1,
                                              const float* __restrict__ fwd2,
                                              const float* __restrict__ bias,
                                              float* __restrict__ out) {
  __shared__ float st[16 * 360];  // [ic][18 rows][20]
  int tid = threadIdx.x;
  int b = blockIdx.y;
  int R0 = (blockIdx.x >> 3) * 16, C0 = (blockIdx.x & 7) * 16;
  const float* ip = d1 + (size_t)b * 262144;
  for (int i = tid; i < 5184; i += 256) {  // 16 ic x 18 x 18
    int ic = i / 324, rr = (i % 324) / 18, cc = i % 18;
    int r = R0 - 1 + rr, c = C0 - 1 + cc;
    st[ic * 360 + rr * 20 + cc] =
        ((unsigned)r < 128u && (unsigned)c < 128u) ? ip[ic * 16384 + r * 128 + c] : 0.f;
  }
  __syncthreads();
  int lane = tid & 63, wid = tid >> 6;
  int qy = wid >> 1, qx = wid & 1;
  int ty = qy * 8 + (lane >> 3), tx = qx * 8 + (lane & 7);
  float acc[4] = {0.f, 0.f, 0.f, 0.f};
#pragma unroll 1
  for (int ic = 0; ic < 16; ++ic) {
    const float* t = st + ic * 360 + ty * 20 + tx;
    float i3[3][3];
#pragma unroll
    for (int dy = 0; dy < 3; ++dy)
#pragma unroll
      for (int dx = 0; dx < 3; ++dx) i3[dy][dx] = t[dy * 20 + dx];
    const float* wp = fwd2 + ic * 16;  // scalar loads
#pragma unroll
    for (int p = 0; p < 4; ++p) {
      int a = p >> 1, b2 = p & 1;
#pragma unroll
      for (int tp = 0; tp < 4; ++tp) {
        int dy = tp >> 1, dx = tp & 1;
        acc[p] = fmaf(i3[a + dy][b2 + dx], wp[p * 4 + tp], acc[p]);
      }
    }
  }
  float bv = bias[0];
  int Y = 2 * (R0 + ty), X = 2 * (C0 + tx);
  float* op = out + (size_t)b * 65536 + Y * 256 + X;
  float2 r0v, r1v;
  r0v.x = fminf(1.0f, fmaxf(-1.0f, acc[0] + bv));
  r0v.y = fminf(1.0f, fmaxf(-1.0f, acc[1] + bv));
  r1v.x = fminf(1.0f, fmaxf(-1.0f, acc[2] + bv));
  r1v.y = fminf(1.0f, fmaxf(-1.0f, acc[3] + bv));
  *(float2*)op = r0v;
  *(float2*)(op + 256) = r1v;
}

extern "C" void kernel_launch(void* const* d_in, const int* in_sizes, int n_in,
                              void* d_out, int out_size, void* d_ws, size_t ws_size,
                              hipStream_t stream) {
  const float* x   = (const float*)d_in[0];
  const float* e1w = (const float*)d_in[1];
  const float* e1b = (const float*)d_in[2];
  const float* e2w = (const float*)d_in[3];
  const float* e2b = (const float*)d_in[4];
  const float* cb  = (const float*)d_in[5];
  const float* d1w = (const float*)d_in[6];
  const float* d1b = (const float*)d_in[7];
  const float* d2w = (const float*)d_in[8];
  const float* d2b = (const float*)d_in[9];

  float* out = (float*)d_out;
  float* y       = out;                       // [32,1,256,256] = 2097152
  float* idxout  = out + 2097152;             // [32,64,64]     = 131072 (as float)
  float* lossout = out + 2097152 + 131072;    // scalar

  float* ws = (float*)d_ws;
  float* h1      = ws;                        // h1t[32][128][128][16] = 8388608 floats
  float* h2      = ws + 8388608;              // [32,32,64,64]   = 4194304 floats
  float* partial = ws + 12582912;             // 512 floats
  float* fwd1    = ws + 12588032;             // 8192 (offset kept from prior rounds)
  float* fwd2    = ws + 12596224;             // 256
  float* d1o     = h1;                        // dec1 output reuses h1 (after vq)

  // Scratch in the y-region of out (written by k_fold, consumed before k_dec2
  // overwrites all of y): cbs 24576 floats, csqg 512, wfrag 6912.
  unsigned short* cbs = (unsigned short*)out;          // 49152 bf16
  float* csqg = out + 24576;                           // 512
  unsigned short* wfrag = (unsigned short*)(out + 25088);  // 13824 bf16

  k_fold<<<dim3(153), 256, 0, stream>>>(e2w, d1w, d2w, cb, fwd1, fwd2, cbs, csqg, wfrag);
  k_enc1<<<dim3(2048), 256, 0, stream>>>(x, e1w, e1b, h1);
  k_enc2<<<dim3(64, 32), 256, 0, stream>>>(h1, wfrag, e2b, h2);
  k_vq<<<dim3(512), 256, 0, stream>>>(h2, cb, cbs, csqg, idxout, partial);
  k_loss<<<dim3(1), 256, 0, stream>>>(partial, lossout);
  k_dec1<<<dim3(32, 32), 256, 0, stream>>>(h2, fwd1, d1b, d1o);
  k_dec2<<<dim3(64, 32), 256, 0, stream>>>(d1o, fwd2, d2b, y);
}

// Round 10
// 256.172 us; speedup vs baseline: 1.4011x; 1.0739x over previous
//
#include <hip/hip_runtime.h>
#include <math.h>

#define GELU(v) (0.5f * (v) * (1.0f + erff((v)*0.70710678118654752440f)))

typedef __attribute__((ext_vector_type(8))) short short8;
typedef __attribute__((ext_vector_type(4))) float f32x4;
typedef __attribute__((ext_vector_type(16))) float f32x16;
#define MFMA16 __builtin_amdgcn_mfma_f32_16x16x32_bf16
#define MFMA32 __builtin_amdgcn_mfma_f32_32x32x16_bf16

// Exact 3-way bf16 split of fp32 (24 = 3x8 mantissa bits, truncation):
// v == p1 + p2 + p3 exactly (each pi representable in bf16).
#define SPLIT3(V, U1, U2, U3)                                                  \
  unsigned U1 = __float_as_uint(V) & 0xFFFF0000u;                              \
  float _r1 = (V)-__uint_as_float(U1);                                         \
  unsigned U2 = __float_as_uint(_r1) & 0xFFFF0000u;                            \
  float _r2 = _r1 - __uint_as_float(U2);                                       \
  unsigned U3 = __float_as_uint(_r2) & 0xFFFF0000u;

// ---------------- Setup: fold weights + split codebook/enc2-weights ------------
// fwd1[grp(2)][ic(32)][phase(4)][tap(4)][o(8)]: dec1 up2-folded    (8192)
// fwd2[ic(16)][phase(4)][tap(4)]              : dec2 up2-folded    (256)
// cbs[part(3)][code(512)][ch(32)] bf16        : codebook 3-way split
// csqg[512]                                   : ||c||^2
// wfrag[part(3)][tap(9)][lane(64)][j(8)] bf16 : enc2 W B-fragments, lane order
__global__ __launch_bounds__(256) void k_fold(const float* __restrict__ e2w,
                                              const float* __restrict__ d1w,
                                              const float* __restrict__ d2w,
                                              const float* __restrict__ cb,
                                              float* __restrict__ fwd1,
                                              float* __restrict__ fwd2,
                                              unsigned short* __restrict__ cbs,
                                              float* __restrict__ csqg,
                                              unsigned short* __restrict__ wfrag) {
  int i = blockIdx.x * 256 + threadIdx.x;
  if (i < 8192) {
    int j = i;
    int o = j & 7, pt = (j >> 3) & 15, ic = (j >> 7) & 31, grp = j >> 12;
    int a = pt >> 3, b2 = (pt >> 2) & 1, dy = (pt >> 1) & 1, dx = pt & 1;
    const float* wsrc = d1w + ((grp * 8 + o) * 32 + ic) * 9;
    float s = 0.f;
    for (int ky = 0; ky < 3; ++ky) {
      int rm = (a == 0) ? (ky == 0 ? 0 : 1) : (ky == 2 ? 1 : 0);
      if (rm != dy) continue;
      for (int kx = 0; kx < 3; ++kx) {
        int cm = (b2 == 0) ? (kx == 0 ? 0 : 1) : (kx == 2 ? 1 : 0);
        if (cm == dx) s += wsrc[ky * 3 + kx];
      }
    }
    fwd1[j] = s;
  } else if (i < 8448) {
    int j = i - 8192;
    int pt = j & 15, ic = j >> 4;
    int a = pt >> 3, b2 = (pt >> 2) & 1, dy = (pt >> 1) & 1, dx = pt & 1;
    const float* wsrc = d2w + ic * 9;
    float s = 0.f;
    for (int ky = 0; ky < 3; ++ky) {
      int rm = (a == 0) ? (ky == 0 ? 0 : 1) : (ky == 2 ? 1 : 0);
      if (rm != dy) continue;
      for (int kx = 0; kx < 3; ++kx) {
        int cm = (b2 == 0) ? (kx == 0 ? 0 : 1) : (kx == 2 ? 1 : 0);
        if (cm == dx) s += wsrc[ky * 3 + kx];
      }
    }
    fwd2[j] = s;
  } else if (i < 24832) {
    int j = i - 8448;  // [0, 16384): code = j>>5, ch = j&31
    float v = cb[j];
    SPLIT3(v, u1, u2, u3)
    cbs[j] = (unsigned short)(u1 >> 16);
    cbs[16384 + j] = (unsigned short)(u2 >> 16);
    cbs[32768 + j] = (unsigned short)(u3 >> 16);
  } else if (i < 25344) {
    int c = i - 24832;
    const float* row = cb + (size_t)c * 32;
    float s = 0.f;
#pragma unroll
    for (int d = 0; d < 32; ++d) s = fmaf(row[d], row[d], s);
    csqg[c] = s;
  } else if (i < 39168) {
    int j = i - 25344;  // [0, 13824)
    int p = j / 4608, rem = j - p * 4608;
    int t = rem >> 9, l2 = (rem >> 3) & 63, jj = rem & 7;
    float v = e2w[((l2 & 31) * 16 + ((l2 >> 5) * 8 + jj)) * 9 + t];
    SPLIT3(v, u1, u2, u3)
    unsigned short r = (p == 0)   ? (unsigned short)(u1 >> 16)
                       : (p == 1) ? (unsigned short)(u2 >> 16)
                                  : (unsigned short)(u3 >> 16);
    wfrag[j] = r;
  }
}

// ---------------- Kernel A: conv1 (1->16) + maxpool2 + gelu --------------------
// Output layout h1t[b][y][x][ic16] (ic contiguous) for enc2's MFMA staging.
__global__ __launch_bounds__(256) void k_enc1(const float* __restrict__ x,
                                              const float* __restrict__ w,
                                              const float* __restrict__ bias,
                                              float* __restrict__ h1) {
  int gid = blockIdx.x * 256 + threadIdx.x;
  int xx = gid & 127, yy = (gid >> 7) & 127, b = gid >> 14;
  const float* xp = x + (size_t)b * 65536;
  int r0 = 2 * yy - 1, c0 = 2 * xx - 1;
  float in[4][4];
#pragma unroll
  for (int i = 0; i < 4; ++i) {
    int r = r0 + i;
    bool rv = (unsigned)r < 256u;
#pragma unroll
    for (int j = 0; j < 4; ++j) {
      int c = c0 + j;
      in[i][j] = (rv && (unsigned)c < 256u) ? xp[r * 256 + c] : 0.0f;
    }
  }
  float vout[16];
#pragma unroll
  for (int oc = 0; oc < 16; ++oc) {
    const float* wp = w + oc * 9;  // uniform -> s_load
    float s00 = 0.f, s01 = 0.f, s10 = 0.f, s11 = 0.f;
#pragma unroll
    for (int ky = 0; ky < 3; ++ky)
#pragma unroll
      for (int kx = 0; kx < 3; ++kx) {
        float wv = wp[ky * 3 + kx];
        s00 = fmaf(in[ky][kx], wv, s00);
        s01 = fmaf(in[ky][kx + 1], wv, s01);
        s10 = fmaf(in[ky + 1][kx], wv, s10);
        s11 = fmaf(in[ky + 1][kx + 1], wv, s11);
      }
    float m = fmaxf(fmaxf(s00, s01), fmaxf(s10, s11)) + bias[oc];
    vout[oc] = GELU(m);
  }
  float* op = h1 + (size_t)b * 262144 + ((size_t)yy * 128 + xx) * 16;
#pragma unroll
  for (int q = 0; q < 4; ++q) {
    float4 vq;
    vq.x = vout[4 * q + 0]; vq.y = vout[4 * q + 1];
    vq.z = vout[4 * q + 2]; vq.w = vout[4 * q + 3];
    *(float4*)(op + 4 * q) = vq;
  }
}

// ---------------- Kernel B: conv2 (16->32) + maxpool2 via split MFMA -----------
// (r9-verified: idx-exact, absmax unchanged.)
__global__ __launch_bounds__(256) void k_enc2(const float* __restrict__ h1,
                                              const unsigned short* __restrict__ wfrag,
                                              const float* __restrict__ bias,
                                              float* __restrict__ h2) {
  __shared__ __align__(16) unsigned short sA[3 * 2 * 10 * 34 * 8];  // 32640 B
  const int PP = 2 * 10 * 34 * 8;  // part-plane stride (shorts)
  int tid = threadIdx.x;
  int b = blockIdx.y;
  int X0 = (blockIdx.x & 3) * 32, Y0 = (blockIdx.x >> 2) * 8;
  const float* ip = h1 + (size_t)b * 262144;
  for (int i = tid; i < 5440; i += 256) {  // 10 y x 34 x x 16 ic
    int yy = i / 544, rem = i % 544, xx = rem >> 4, ic = rem & 15;
    int y = Y0 - 1 + yy, xg = X0 - 1 + xx;
    float v = ((unsigned)y < 128u && (unsigned)xg < 128u)
                  ? ip[((size_t)y * 128 + xg) * 16 + ic] : 0.f;
    SPLIT3(v, u1, u2, u3)
    int si = (((ic >> 3) * 10 + yy) * 34 + xx) * 8 + (ic & 7);
    sA[si] = (unsigned short)(u1 >> 16);
    sA[PP + si] = (unsigned short)(u2 >> 16);
    sA[2 * PP + si] = (unsigned short)(u3 >> 16);
  }
  __syncthreads();

  int l = tid & 63, w = tid >> 6;
  int xl = l & 31, ich = l >> 5;
  f32x16 acc0[2], acc1[2];
#pragma unroll
  for (int s = 0; s < 2; ++s)
#pragma unroll
    for (int r = 0; r < 16; ++r) { acc0[s][r] = 0.f; acc1[s][r] = 0.f; }

#pragma unroll
  for (int t = 0; t < 9; ++t) {
    int dy = t / 3, dx = t % 3;
    int s = t & 1;
    const unsigned short* wb = wfrag + t * 512 + l * 8;  // [p][t][l][8]
    short8 bf1 = *(const short8*)(wb);
    short8 bf2 = *(const short8*)(wb + 4608);
    short8 bf3 = *(const short8*)(wb + 9216);
    int g0 = ((ich * 10) + (2 * w + dy)) * 34 + xl + dx;  // tile ty=0
    const unsigned short* a0p = sA + g0 * 8;
    short8 a01 = *(const short8*)(a0p);
    short8 a02 = *(const short8*)(a0p + PP);
    short8 a03 = *(const short8*)(a0p + 2 * PP);
    const unsigned short* a1p = a0p + 34 * 8;             // tile ty=1 (+1 y row)
    short8 a11 = *(const short8*)(a1p);
    short8 a12 = *(const short8*)(a1p + PP);
    short8 a13 = *(const short8*)(a1p + 2 * PP);
    acc0[s] = MFMA32(a01, bf1, acc0[s], 0, 0, 0);
    acc0[s] = MFMA32(a01, bf2, acc0[s], 0, 0, 0);
    acc0[s] = MFMA32(a02, bf1, acc0[s], 0, 0, 0);
    acc0[s] = MFMA32(a02, bf2, acc0[s], 0, 0, 0);
    acc0[s] = MFMA32(a01, bf3, acc0[s], 0, 0, 0);
    acc0[s] = MFMA32(a03, bf1, acc0[s], 0, 0, 0);
    acc1[s] = MFMA32(a11, bf1, acc1[s], 0, 0, 0);
    acc1[s] = MFMA32(a11, bf2, acc1[s], 0, 0, 0);
    acc1[s] = MFMA32(a12, bf1, acc1[s], 0, 0, 0);
    acc1[s] = MFMA32(a12, bf2, acc1[s], 0, 0, 0);
    acc1[s] = MFMA32(a11, bf3, acc1[s], 0, 0, 0);
    acc1[s] = MFMA32(a13, bf1, acc1[s], 0, 0, 0);
  }

  float bv = bias[l & 31];
  int ypool = (Y0 >> 1) + w;
  float* op = h2 + (size_t)b * 131072 + (size_t)(l & 31) * 4096 + ypool * 64 + (X0 >> 1);
#pragma unroll
  for (int k = 0; k < 8; ++k) {
    float e0 = (acc0[0][2 * k] + acc0[1][2 * k]);
    float o0 = (acc0[0][2 * k + 1] + acc0[1][2 * k + 1]);
    float e1 = (acc1[0][2 * k] + acc1[1][2 * k]);
    float o1 = (acc1[0][2 * k + 1] + acc1[1][2 * k + 1]);
    float m = fmaxf(fmaxf(e0, o0), fmaxf(e1, o1)) + bv;
    int row = ((2 * k) & 3) + 8 * ((2 * k) >> 2) + 4 * ich;  // D-row of reg 2k
    op[row >> 1] = m;
  }
}

// ---------------- Kernel C: VQ via exact-split bf16 MFMA (v2) ------------------
// r10 changes (one theory: cut the 83% non-MFMA time):
//  1. distance-2 B prefetch: tile ct+2 issued before computing ct+1 -> ~232cyc
//     compute covers L2 latency (was 1-tile = ~116cyc, exposed).
//  2. analytic loss: ||q-f||^2 = d_best + ||f||^2  (fsq from staging; bd stashed
//     in LDS) -> epilogue is a fully-parallel coalesced quantize, no re-read,
//     no idle-lane serial loop.
//  3. packed ds_write_b128 staging (12 stores/thread, min-bank-access pattern)
//     instead of 96 scalar b16 (8-way conflicts, 2.31M conflict cycles).
__global__ __launch_bounds__(256) void k_vq(float* __restrict__ h2,
                                            const float* __restrict__ cb,
                                            const unsigned short* __restrict__ cbs,
                                            const float* __restrict__ csqg,
                                            float* __restrict__ idxout,
                                            float* __restrict__ partial) {
  __shared__ __align__(16) unsigned short sA[3 * 256 * 40];  // [part][tok][40]
  __shared__ float sFsq[256];
  __shared__ float sBd[256];
  __shared__ int sBi[256];
  __shared__ float sred[4];
  int tid = threadIdx.x;
  int blk = blockIdx.x;
  int t0 = blk * 256;
  size_t abase = (size_t)(t0 >> 12) * 131072 + (t0 & 4095);

  // ---- stage + split tokens (thread = token); packed b128 writes; ||f||^2 ----
  {
    const float* src = h2 + abase + tid;
    float fsq = 0.f;
#pragma unroll
    for (int g = 0; g < 4; ++g) {
      short8 p1, p2, p3;
#pragma unroll
      for (int e = 0; e < 8; ++e) {
        float v = src[(g * 8 + e) * 4096];
        fsq = fmaf(v, v, fsq);
        SPLIT3(v, u1, u2, u3)
        p1[e] = (short)(u1 >> 16);
        p2[e] = (short)(u2 >> 16);
        p3[e] = (short)(u3 >> 16);
      }
      *(short8*)(sA + (0 * 256 + tid) * 40 + g * 8) = p1;
      *(short8*)(sA + (1 * 256 + tid) * 40 + g * 8) = p2;
      *(short8*)(sA + (2 * 256 + tid) * 40 + g * 8) = p3;
    }
    sFsq[tid] = fsq;
  }
  __syncthreads();

  int l = tid & 63, w = tid >> 6;
  int cl = l & 15, k0 = (l >> 4) * 8;
  short8 af[3][4];
#pragma unroll
  for (int p = 0; p < 3; ++p)
#pragma unroll
    for (int tq = 0; tq < 4; ++tq) {
      int tok = w * 64 + tq * 16 + cl;
      af[p][tq] = *(const short8*)(sA + (p * 256 + tok) * 40 + k0);
    }

  float bd[4][4];
  int bi[4][4];
#pragma unroll
  for (int a = 0; a < 4; ++a)
#pragma unroll
    for (int b = 0; b < 4; ++b) { bd[a][b] = 3.4e38f; bi[a][b] = 0; }

#define LOADB(S, CT)                                                           \
  {                                                                            \
    int col = (CT)*16 + cl;                                                    \
    b1##S = *(const short8*)(cbs + (0 * 512 + col) * 32 + k0);                 \
    b2##S = *(const short8*)(cbs + (1 * 512 + col) * 32 + k0);                 \
    b3##S = *(const short8*)(cbs + (2 * 512 + col) * 32 + k0);                 \
    cq##S = csqg[col];                                                         \
  }
#define COMPUTE(S, CT)                                                         \
  {                                                                            \
    _Pragma("unroll") for (int tq = 0; tq < 4; ++tq) {                         \
      f32x4 acc = {0.f, 0.f, 0.f, 0.f};                                        \
      acc = MFMA16(af[0][tq], b1##S, acc, 0, 0, 0);                            \
      acc = MFMA16(af[0][tq], b2##S, acc, 0, 0, 0);                            \
      acc = MFMA16(af[1][tq], b1##S, acc, 0, 0, 0);                            \
      acc = MFMA16(af[1][tq], b2##S, acc, 0, 0, 0);                            \
      acc = MFMA16(af[0][tq], b3##S, acc, 0, 0, 0);                            \
      acc = MFMA16(af[2][tq], b1##S, acc, 0, 0, 0);                            \
      _Pragma("unroll") for (int i = 0; i < 4; ++i) {                          \
        float d = fmaf(-2.f, acc[i], cq##S);                                   \
        if (d < bd[tq][i]) { bd[tq][i] = d; bi[tq][i] = (CT)*16 + cl; }        \
      }                                                                        \
    }                                                                          \
  }

  short8 b1A, b2A, b3A, b1B, b2B, b3B;
  float cqA, cqB;
  LOADB(A, 0)
  LOADB(B, 1)
#pragma unroll 1
  for (int ct = 0; ct < 32; ct += 2) {
    COMPUTE(A, ct)
    LOADB(A, (ct + 2) & 31)  // distance-2 prefetch; wrap: in-bounds, unused
    COMPUTE(B, ct + 1)
    LOADB(B, (ct + 3) & 31)
  }
#undef LOADB
#undef COMPUTE

  // ---- cross-lane argmin over 16 code-slices (lexicographic) ----
#pragma unroll
  for (int tq = 0; tq < 4; ++tq)
#pragma unroll
    for (int i = 0; i < 4; ++i)
#pragma unroll
      for (int m = 1; m < 16; m <<= 1) {
        float od = __shfl_xor(bd[tq][i], m, 64);
        int ob = __shfl_xor(bi[tq][i], m, 64);
        if (od < bd[tq][i] || (od == bd[tq][i] && ob < bi[tq][i])) {
          bd[tq][i] = od;
          bi[tq][i] = ob;
        }
      }
  // one lane per 16-group publishes its 4 D-rows (token = w*64+tq*16+(l>>4)*4+i)
  if (cl == 0) {
#pragma unroll
    for (int tq = 0; tq < 4; ++tq)
#pragma unroll
      for (int i = 0; i < 4; ++i) {
        int tokl = w * 64 + tq * 16 + (l >> 4) * 4 + i;
        sBi[tokl] = bi[tq][i];
        sBd[tokl] = bd[tq][i];
      }
  }
  __syncthreads();

  // ---- epilogue: coalesced quantize (thread = token) + analytic loss ----
  int bsel = sBi[tid];
  idxout[t0 + tid] = (float)bsel;
  const float4* qr = (const float4*)(cb + (size_t)bsel * 32);
  float* hp = h2 + abase + tid;
#pragma unroll
  for (int g = 0; g < 8; ++g) {
    float4 qv = qr[g];
    hp[(4 * g + 0) * 4096] = qv.x;
    hp[(4 * g + 1) * 4096] = qv.y;
    hp[(4 * g + 2) * 4096] = qv.z;
    hp[(4 * g + 3) * 4096] = qv.w;
  }
  float loss = sBd[tid] + sFsq[tid];  // ||q-f||^2 = csq - 2 f.c + ||f||^2
#pragma unroll
  for (int off = 32; off > 0; off >>= 1) loss += __shfl_down(loss, off, 64);
  if (l == 0) sred[w] = loss;
  __syncthreads();
  if (tid == 0) partial[blk] = (sred[0] + sred[1]) + (sred[2] + sred[3]);
}

// ---------------- Kernel F: finalize commit loss (512 partials) ----------------
__global__ __launch_bounds__(256) void k_loss(const float* __restrict__ partial,
                                              float* __restrict__ lossout) {
  __shared__ float sred[4];
  int tid = threadIdx.x;
  float v = partial[tid] + partial[tid + 256];
#pragma unroll
  for (int off = 32; off > 0; off >>= 1) v += __shfl_down(v, off, 64);
  if ((tid & 63) == 0) sred[tid >> 6] = v;
  __syncthreads();
  if (tid == 0)
    lossout[0] = ((sred[0] + sred[1]) + (sred[2] + sred[3])) * (1.0f / 4194304.0f);
}

// ---------------- Kernel D: up2 + conv (32->16) + gelu, phase-folded -----------
__device__ __forceinline__ void d1_loadi3(float (&dst)[3][3], const float* t) {
#pragma unroll
  for (int dy = 0; dy < 3; ++dy)
#pragma unroll
    for (int dx = 0; dx < 3; ++dx) dst[dy][dx] = t[dy * 20 + dx];
}
__device__ __forceinline__ void d1_fma(float (&acc)[4][8], const float (&i3)[3][3],
                                       const float* wp) {
#pragma unroll
  for (int p = 0; p < 4; ++p) {
    int a = p >> 1, b2 = p & 1;
#pragma unroll
    for (int tp = 0; tp < 4; ++tp) {
      int dy = tp >> 1, dx = tp & 1;
      float iv = i3[a + dy][b2 + dx];
#pragma unroll
      for (int o2 = 0; o2 < 8; ++o2)
        acc[p][o2] = fmaf(iv, wp[(p * 4 + tp) * 8 + o2], acc[p][o2]);
    }
  }
}
__global__ __launch_bounds__(256) void k_dec1(const float* __restrict__ q,
                                              const float* __restrict__ fwd1,
                                              const float* __restrict__ bias,
                                              float* __restrict__ o) {
  __shared__ float st[32 * 200];  // [ic][10 rows][20]
  int tid = threadIdx.x;
  int b = blockIdx.y;
  int R0 = (blockIdx.x >> 2) * 8, C0 = (blockIdx.x & 3) * 16;
  const float* ip = q + (size_t)b * 131072;
  for (int i = tid; i < 5760; i += 256) {  // 32 ic x 10 x 18
    int ic = i / 180, rr = (i % 180) / 18, cc = i % 18;
    int r = R0 - 1 + rr, c = C0 - 1 + cc;
    st[ic * 200 + rr * 20 + cc] =
        ((unsigned)r < 64u && (unsigned)c < 64u) ? ip[ic * 4096 + r * 64 + c] : 0.f;
  }
  __syncthreads();
  int lane = tid & 63, wid = tid >> 6;
  int qx = wid & 1;
  int grp = __builtin_amdgcn_readfirstlane(wid >> 1);
  int ty = lane >> 3, tx = qx * 8 + (lane & 7);
  float acc[4][8];
#pragma unroll
  for (int p = 0; p < 4; ++p)
#pragma unroll
    for (int o2 = 0; o2 < 8; ++o2) acc[p][o2] = 0.f;
  const float* wb = fwd1 + grp * 4096;
  const float* tb = st + ty * 20 + tx;
  float i3A[3][3], i3B[3][3];
  d1_loadi3(i3A, tb);
#pragma unroll 1
  for (int ic = 0; ic < 32; ic += 2) {
    d1_loadi3(i3B, tb + (ic + 1) * 200);
    d1_fma(acc, i3A, wb + ic * 128);
    d1_loadi3(i3A, tb + ((ic + 2) & 31) * 200);  // wrap: harmless re-read
    d1_fma(acc, i3B, wb + (ic + 1) * 128);
  }
  int Y = 2 * (R0 + ty), X = 2 * (C0 + tx);
#pragma unroll
  for (int o2 = 0; o2 < 8; ++o2) {
    int oc = grp * 8 + o2;
    float bb = bias[oc];
    float* p = o + (size_t)b * 262144 + (size_t)oc * 16384 + Y * 128 + X;
    float2 r0v, r1v;
    r0v.x = GELU(acc[0][o2] + bb);
    r0v.y = GELU(acc[1][o2] + bb);
    r1v.x = GELU(acc[2][o2] + bb);
    r1v.y = GELU(acc[3][o2] + bb);
    *(float2*)p = r0v;
    *(float2*)(p + 128) = r1v;
  }
}

// ---------------- Kernel E: up2 + conv (16->1) + clip, phase-folded ------------
__global__ __launch_bounds__(256) void k_dec2(const float* __restrict__ d1,
                                              const float* __restrict__ fwd2,
                                              const float* __restrict__ bias,
                                              float* __restrict__ out) {
  __shared__ float st[16 * 360];  // [ic][18 rows][20]
  int tid = threadIdx.x;
  int b = blockIdx.y;
  int R0 = (blockIdx.x >> 3) * 16, C0 = (blockIdx.x & 7) * 16;
  const float* ip = d1 + (size_t)b * 262144;
  for (int i = tid; i < 5184; i += 256) {  // 16 ic x 18 x 18
    int ic = i / 324, rr = (i % 324) / 18, cc = i % 18;
    int r = R0 - 1 + rr, c = C0 - 1 + cc;
    st[ic * 360 + rr * 20 + cc] =
        ((unsigned)r < 128u && (unsigned)c < 128u) ? ip[ic * 16384 + r * 128 + c] : 0.f;
  }
  __syncthreads();
  int lane = tid & 63, wid = tid >> 6;
  int qy = wid >> 1, qx = wid & 1;
  int ty = qy * 8 + (lane >> 3), tx = qx * 8 + (lane & 7);
  float acc[4] = {0.f, 0.f, 0.f, 0.f};
#pragma unroll 1
  for (int ic = 0; ic < 16; ++ic) {
    const float* t = st + ic * 360 + ty * 20 + tx;
    float i3[3][3];
#pragma unroll
    for (int dy = 0; dy < 3; ++dy)
#pragma unroll
      for (int dx = 0; dx < 3; ++dx) i3[dy][dx] = t[dy * 20 + dx];
    const float* wp = fwd2 + ic * 16;  // scalar loads
#pragma unroll
    for (int p = 0; p < 4; ++p) {
      int a = p >> 1, b2 = p & 1;
#pragma unroll
      for (int tp = 0; tp < 4; ++tp) {
        int dy = tp >> 1, dx = tp & 1;
        acc[p] = fmaf(i3[a + dy][b2 + dx], wp[p * 4 + tp], acc[p]);
      }
    }
  }
  float bv = bias[0];
  int Y = 2 * (R0 + ty), X = 2 * (C0 + tx);
  float* op = out + (size_t)b * 65536 + Y * 256 + X;
  float2 r0v, r1v;
  r0v.x = fminf(1.0f, fmaxf(-1.0f, acc[0] + bv));
  r0v.y = fminf(1.0f, fmaxf(-1.0f, acc[1] + bv));
  r1v.x = fminf(1.0f, fmaxf(-1.0f, acc[2] + bv));
  r1v.y = fminf(1.0f, fmaxf(-1.0f, acc[3] + bv));
  *(float2*)op = r0v;
  *(float2*)(op + 256) = r1v;
}

extern "C" void kernel_launch(void* const* d_in, const int* in_sizes, int n_in,
                              void* d_out, int out_size, void* d_ws, size_t ws_size,
                              hipStream_t stream) {
  const float* x   = (const float*)d_in[0];
  const float* e1w = (const float*)d_in[1];
  const float* e1b = (const float*)d_in[2];
  const float* e2w = (const float*)d_in[3];
  const float* e2b = (const float*)d_in[4];
  const float* cb  = (const float*)d_in[5];
  const float* d1w = (const float*)d_in[6];
  const float* d1b = (const float*)d_in[7];
  const float* d2w = (const float*)d_in[8];
  const float* d2b = (const float*)d_in[9];

  float* out = (float*)d_out;
  float* y       = out;                       // [32,1,256,256] = 2097152
  float* idxout  = out + 2097152;             // [32,64,64]     = 131072 (as float)
  float* lossout = out + 2097152 + 131072;    // scalar

  float* ws = (float*)d_ws;
  float* h1      = ws;                        // h1t[32][128][128][16] = 8388608 floats
  float* h2      = ws + 8388608;              // [32,32,64,64]   = 4194304 floats
  float* partial = ws + 12582912;             // 512 floats
  float* fwd1    = ws + 12588032;             // 8192
  float* fwd2    = ws + 12596224;             // 256
  float* d1o     = h1;                        // dec1 output reuses h1 (after vq)

  // Scratch in the y-region of out (written by k_fold, consumed before k_dec2
  // overwrites all of y): cbs 24576 floats, csqg 512, wfrag 6912.
  unsigned short* cbs = (unsigned short*)out;          // 49152 bf16
  float* csqg = out + 24576;                           // 512
  unsigned short* wfrag = (unsigned short*)(out + 25088);  // 13824 bf16

  k_fold<<<dim3(153), 256, 0, stream>>>(e2w, d1w, d2w, cb, fwd1, fwd2, cbs, csqg, wfrag);
  k_enc1<<<dim3(2048), 256, 0, stream>>>(x, e1w, e1b, h1);
  k_enc2<<<dim3(64, 32), 256, 0, stream>>>(h1, wfrag, e2b, h2);
  k_vq<<<dim3(512), 256, 0, stream>>>(h2, cb, cbs, csqg, idxout, partial);
  k_loss<<<dim3(1), 256, 0, stream>>>(partial, lossout);
  k_dec1<<<dim3(32, 32), 256, 0, stream>>>(h2, fwd1, d1b, d1o);
  k_dec2<<<dim3(64, 32), 256, 0, stream>>>(d1o, fwd2, d2b, y);
}

// Round 11
// 242.514 us; speedup vs baseline: 1.4800x; 1.0563x over previous
//
#include <hip/hip_runtime.h>
#include <math.h>

#define GELU(v) (0.5f * (v) * (1.0f + erff((v)*0.70710678118654752440f)))

typedef __attribute__((ext_vector_type(8))) short short8;
typedef __attribute__((ext_vector_type(4))) float f32x4;
typedef __attribute__((ext_vector_type(16))) float f32x16;
#define MFMA16 __builtin_amdgcn_mfma_f32_16x16x32_bf16
#define MFMA32 __builtin_amdgcn_mfma_f32_32x32x16_bf16

// Exact 3-way bf16 split of fp32 (24 = 3x8 mantissa bits, truncation):
// v == p1 + p2 + p3 exactly (each pi representable in bf16).
#define SPLIT3(V, U1, U2, U3)                                                  \
  unsigned U1 = __float_as_uint(V) & 0xFFFF0000u;                              \
  float _r1 = (V)-__uint_as_float(U1);                                         \
  unsigned U2 = __float_as_uint(_r1) & 0xFFFF0000u;                            \
  float _r2 = _r1 - __uint_as_float(U2);                                       \
  unsigned U3 = __float_as_uint(_r2) & 0xFFFF0000u;

// ---------------- Setup: fold weights + split codebook/enc2/dec1 weights -------
// fwd2[ic(16)][phase(4)][tap(4)]              : dec2 up2-folded    (256)
// cbs[part(3)][code(512)][ch(32)] bf16        : codebook 3-way split
// csqg[512]                                   : ||c||^2
// wfrag[part(3)][tap(9)][lane(64)][j(8)] bf16 : enc2 W B-fragments
// wfd1[slot(108)][lane(64)][j(8)] bf16        : dec1 W B-fragments, phase-packed
//   slot = cx*36 + ry*12 + kh*6 + pp*3 + part; lane: col c=l&31 -> b2=c>>4,
//   oc=c&15; k=(l>>5)*8+j -> ic=kh*16+k; ph=(a=pp, b2); tap dy=ry-a, dx=cx-b2;
//   value = valid(dy,dx in [0,1]) ? part(fold(oc,ic,ph,tap)) : 0.
__global__ __launch_bounds__(256) void k_fold(const float* __restrict__ e2w,
                                              const float* __restrict__ d1w,
                                              const float* __restrict__ d2w,
                                              const float* __restrict__ cb,
                                              float* __restrict__ fwd2,
                                              unsigned short* __restrict__ cbs,
                                              float* __restrict__ csqg,
                                              unsigned short* __restrict__ wfrag,
                                              unsigned short* __restrict__ wfd1) {
  int i = blockIdx.x * 256 + threadIdx.x;
  if (i < 256) {
    int j = i;
    int pt = j & 15, ic = j >> 4;
    int a = pt >> 3, b2 = (pt >> 2) & 1, dy = (pt >> 1) & 1, dx = pt & 1;
    const float* wsrc = d2w + ic * 9;
    float s = 0.f;
    for (int ky = 0; ky < 3; ++ky) {
      int rm = (a == 0) ? (ky == 0 ? 0 : 1) : (ky == 2 ? 1 : 0);
      if (rm != dy) continue;
      for (int kx = 0; kx < 3; ++kx) {
        int cm = (b2 == 0) ? (kx == 0 ? 0 : 1) : (kx == 2 ? 1 : 0);
        if (cm == dx) s += wsrc[ky * 3 + kx];
      }
    }
    fwd2[j] = s;
  } else if (i < 16640) {
    int j = i - 256;  // [0, 16384): code = j>>5, ch = j&31
    float v = cb[j];
    SPLIT3(v, u1, u2, u3)
    cbs[j] = (unsigned short)(u1 >> 16);
    cbs[16384 + j] = (unsigned short)(u2 >> 16);
    cbs[32768 + j] = (unsigned short)(u3 >> 16);
  } else if (i < 17152) {
    int c = i - 16640;
    const float* row = cb + (size_t)c * 32;
    float s = 0.f;
#pragma unroll
    for (int d = 0; d < 32; ++d) s = fmaf(row[d], row[d], s);
    csqg[c] = s;
  } else if (i < 30976) {
    int j = i - 17152;  // [0, 13824)
    int p = j / 4608, rem = j - p * 4608;
    int t = rem >> 9, l2 = (rem >> 3) & 63, jj = rem & 7;
    float v = e2w[((l2 & 31) * 16 + ((l2 >> 5) * 8 + jj)) * 9 + t];
    SPLIT3(v, u1, u2, u3)
    unsigned short r = (p == 0)   ? (unsigned short)(u1 >> 16)
                       : (p == 1) ? (unsigned short)(u2 >> 16)
                                  : (unsigned short)(u3 >> 16);
    wfrag[j] = r;
  } else if (i < 86272) {
    int j = i - 30976;  // [0, 55296)
    int slot = j >> 9, l2 = (j >> 3) & 63, jj = j & 7;
    int cx = slot / 36, rem = slot % 36;
    int r3 = rem / 12, rem2 = rem % 12;
    int kh = rem2 / 6, rem3 = rem2 % 6;
    int pp = rem3 / 3, part = rem3 % 3;
    int c = l2 & 31, hi = l2 >> 5;
    int oc = c & 15, b2 = c >> 4;
    int ic = kh * 16 + hi * 8 + jj;
    int dy = r3 - pp, dx = cx - b2;
    float s = 0.f;
    if ((unsigned)dy < 2u && (unsigned)dx < 2u) {
      const float* wsrc = d1w + (oc * 32 + ic) * 9;
      for (int ky = 0; ky < 3; ++ky) {
        int rm = (pp == 0) ? (ky == 0 ? 0 : 1) : (ky == 2 ? 1 : 0);
        if (rm != dy) continue;
        for (int kx = 0; kx < 3; ++kx) {
          int cm = (b2 == 0) ? (kx == 0 ? 0 : 1) : (kx == 2 ? 1 : 0);
          if (cm == dx) s += wsrc[ky * 3 + kx];
        }
      }
    }
    SPLIT3(s, u1, u2, u3)
    unsigned short r = (part == 0)   ? (unsigned short)(u1 >> 16)
                       : (part == 1) ? (unsigned short)(u2 >> 16)
                                     : (unsigned short)(u3 >> 16);
    wfd1[j] = r;
  }
}

// ---------------- Kernel A: conv1 (1->16) + maxpool2 + gelu --------------------
__global__ __launch_bounds__(256) void k_enc1(const float* __restrict__ x,
                                              const float* __restrict__ w,
                                              const float* __restrict__ bias,
                                              float* __restrict__ h1) {
  int gid = blockIdx.x * 256 + threadIdx.x;
  int xx = gid & 127, yy = (gid >> 7) & 127, b = gid >> 14;
  const float* xp = x + (size_t)b * 65536;
  int r0 = 2 * yy - 1, c0 = 2 * xx - 1;
  float in[4][4];
#pragma unroll
  for (int i = 0; i < 4; ++i) {
    int r = r0 + i;
    bool rv = (unsigned)r < 256u;
#pragma unroll
    for (int j = 0; j < 4; ++j) {
      int c = c0 + j;
      in[i][j] = (rv && (unsigned)c < 256u) ? xp[r * 256 + c] : 0.0f;
    }
  }
  float vout[16];
#pragma unroll
  for (int oc = 0; oc < 16; ++oc) {
    const float* wp = w + oc * 9;  // uniform -> s_load
    float s00 = 0.f, s01 = 0.f, s10 = 0.f, s11 = 0.f;
#pragma unroll
    for (int ky = 0; ky < 3; ++ky)
#pragma unroll
      for (int kx = 0; kx < 3; ++kx) {
        float wv = wp[ky * 3 + kx];
        s00 = fmaf(in[ky][kx], wv, s00);
        s01 = fmaf(in[ky][kx + 1], wv, s01);
        s10 = fmaf(in[ky + 1][kx], wv, s10);
        s11 = fmaf(in[ky + 1][kx + 1], wv, s11);
      }
    float m = fmaxf(fmaxf(s00, s01), fmaxf(s10, s11)) + bias[oc];
    vout[oc] = GELU(m);
  }
  float* op = h1 + (size_t)b * 262144 + ((size_t)yy * 128 + xx) * 16;
#pragma unroll
  for (int q = 0; q < 4; ++q) {
    float4 vq;
    vq.x = vout[4 * q + 0]; vq.y = vout[4 * q + 1];
    vq.z = vout[4 * q + 2]; vq.w = vout[4 * q + 3];
    *(float4*)(op + 4 * q) = vq;
  }
}

// ---------------- Kernel B: conv2 (16->32) + maxpool2 via split MFMA -----------
// (r9-verified.)
__global__ __launch_bounds__(256) void k_enc2(const float* __restrict__ h1,
                                              const unsigned short* __restrict__ wfrag,
                                              const float* __restrict__ bias,
                                              float* __restrict__ h2) {
  __shared__ __align__(16) unsigned short sA[3 * 2 * 10 * 34 * 8];  // 32640 B
  const int PP = 2 * 10 * 34 * 8;
  int tid = threadIdx.x;
  int b = blockIdx.y;
  int X0 = (blockIdx.x & 3) * 32, Y0 = (blockIdx.x >> 2) * 8;
  const float* ip = h1 + (size_t)b * 262144;
  for (int i = tid; i < 5440; i += 256) {  // 10 y x 34 x x 16 ic
    int yy = i / 544, rem = i % 544, xx = rem >> 4, ic = rem & 15;
    int y = Y0 - 1 + yy, xg = X0 - 1 + xx;
    float v = ((unsigned)y < 128u && (unsigned)xg < 128u)
                  ? ip[((size_t)y * 128 + xg) * 16 + ic] : 0.f;
    SPLIT3(v, u1, u2, u3)
    int si = (((ic >> 3) * 10 + yy) * 34 + xx) * 8 + (ic & 7);
    sA[si] = (unsigned short)(u1 >> 16);
    sA[PP + si] = (unsigned short)(u2 >> 16);
    sA[2 * PP + si] = (unsigned short)(u3 >> 16);
  }
  __syncthreads();

  int l = tid & 63, w = tid >> 6;
  int xl = l & 31, ich = l >> 5;
  f32x16 acc0[2], acc1[2];
#pragma unroll
  for (int s = 0; s < 2; ++s)
#pragma unroll
    for (int r = 0; r < 16; ++r) { acc0[s][r] = 0.f; acc1[s][r] = 0.f; }

#pragma unroll
  for (int t = 0; t < 9; ++t) {
    int dy = t / 3, dx = t % 3;
    int s = t & 1;
    const unsigned short* wb = wfrag + t * 512 + l * 8;
    short8 bf1 = *(const short8*)(wb);
    short8 bf2 = *(const short8*)(wb + 4608);
    short8 bf3 = *(const short8*)(wb + 9216);
    int g0 = ((ich * 10) + (2 * w + dy)) * 34 + xl + dx;
    const unsigned short* a0p = sA + g0 * 8;
    short8 a01 = *(const short8*)(a0p);
    short8 a02 = *(const short8*)(a0p + PP);
    short8 a03 = *(const short8*)(a0p + 2 * PP);
    const unsigned short* a1p = a0p + 34 * 8;
    short8 a11 = *(const short8*)(a1p);
    short8 a12 = *(const short8*)(a1p + PP);
    short8 a13 = *(const short8*)(a1p + 2 * PP);
    acc0[s] = MFMA32(a01, bf1, acc0[s], 0, 0, 0);
    acc0[s] = MFMA32(a01, bf2, acc0[s], 0, 0, 0);
    acc0[s] = MFMA32(a02, bf1, acc0[s], 0, 0, 0);
    acc0[s] = MFMA32(a02, bf2, acc0[s], 0, 0, 0);
    acc0[s] = MFMA32(a01, bf3, acc0[s], 0, 0, 0);
    acc0[s] = MFMA32(a03, bf1, acc0[s], 0, 0, 0);
    acc1[s] = MFMA32(a11, bf1, acc1[s], 0, 0, 0);
    acc1[s] = MFMA32(a11, bf2, acc1[s], 0, 0, 0);
    acc1[s] = MFMA32(a12, bf1, acc1[s], 0, 0, 0);
    acc1[s] = MFMA32(a12, bf2, acc1[s], 0, 0, 0);
    acc1[s] = MFMA32(a11, bf3, acc1[s], 0, 0, 0);
    acc1[s] = MFMA32(a13, bf1, acc1[s], 0, 0, 0);
  }

  float bv = bias[l & 31];
  int ypool = (Y0 >> 1) + w;
  float* op = h2 + (size_t)b * 131072 + (size_t)(l & 31) * 4096 + ypool * 64 + (X0 >> 1);
#pragma unroll
  for (int k = 0; k < 8; ++k) {
    float e0 = (acc0[0][2 * k] + acc0[1][2 * k]);
    float o0 = (acc0[0][2 * k + 1] + acc0[1][2 * k + 1]);
    float e1 = (acc1[0][2 * k] + acc1[1][2 * k]);
    float o1 = (acc1[0][2 * k + 1] + acc1[1][2 * k + 1]);
    float m = fmaxf(fmaxf(e0, o0), fmaxf(e1, o1)) + bv;
    int row = ((2 * k) & 3) + 8 * ((2 * k) >> 2) + 4 * ich;
    op[row >> 1] = m;
  }
}

// ---------------- Kernel C: VQ via exact-split bf16 MFMA (r10 structure) -------
// h2 write-back DELETED: quantized h2 is dead (dec1 now gathers split values
// from cbs via idx). Epilogue = idxout + analytic loss only.
__global__ __launch_bounds__(256) void k_vq(const float* __restrict__ h2,
                                            const unsigned short* __restrict__ cbs,
                                            const float* __restrict__ csqg,
                                            float* __restrict__ idxout,
                                            float* __restrict__ partial) {
  __shared__ __align__(16) unsigned short sA[3 * 256 * 40];  // [part][tok][40]
  __shared__ float sFsq[256];
  __shared__ float sBd[256];
  __shared__ int sBi[256];
  __shared__ float sred[4];
  int tid = threadIdx.x;
  int blk = blockIdx.x;
  int t0 = blk * 256;
  size_t abase = (size_t)(t0 >> 12) * 131072 + (t0 & 4095);

  {
    const float* src = h2 + abase + tid;
    float fsq = 0.f;
#pragma unroll
    for (int g = 0; g < 4; ++g) {
      short8 p1, p2, p3;
#pragma unroll
      for (int e = 0; e < 8; ++e) {
        float v = src[(g * 8 + e) * 4096];
        fsq = fmaf(v, v, fsq);
        SPLIT3(v, u1, u2, u3)
        p1[e] = (short)(u1 >> 16);
        p2[e] = (short)(u2 >> 16);
        p3[e] = (short)(u3 >> 16);
      }
      *(short8*)(sA + (0 * 256 + tid) * 40 + g * 8) = p1;
      *(short8*)(sA + (1 * 256 + tid) * 40 + g * 8) = p2;
      *(short8*)(sA + (2 * 256 + tid) * 40 + g * 8) = p3;
    }
    sFsq[tid] = fsq;
  }
  __syncthreads();

  int l = tid & 63, w = tid >> 6;
  int cl = l & 15, k0 = (l >> 4) * 8;
  short8 af[3][4];
#pragma unroll
  for (int p = 0; p < 3; ++p)
#pragma unroll
    for (int tq = 0; tq < 4; ++tq) {
      int tok = w * 64 + tq * 16 + cl;
      af[p][tq] = *(const short8*)(sA + (p * 256 + tok) * 40 + k0);
    }

  float bd[4][4];
  int bi[4][4];
#pragma unroll
  for (int a = 0; a < 4; ++a)
#pragma unroll
    for (int b = 0; b < 4; ++b) { bd[a][b] = 3.4e38f; bi[a][b] = 0; }

#define LOADB(S, CT)                                                           \
  {                                                                            \
    int col = (CT)*16 + cl;                                                    \
    b1##S = *(const short8*)(cbs + (0 * 512 + col) * 32 + k0);                 \
    b2##S = *(const short8*)(cbs + (1 * 512 + col) * 32 + k0);                 \
    b3##S = *(const short8*)(cbs + (2 * 512 + col) * 32 + k0);                 \
    cq##S = csqg[col];                                                         \
  }
#define COMPUTE(S, CT)                                                         \
  {                                                                            \
    _Pragma("unroll") for (int tq = 0; tq < 4; ++tq) {                         \
      f32x4 acc = {0.f, 0.f, 0.f, 0.f};                                        \
      acc = MFMA16(af[0][tq], b1##S, acc, 0, 0, 0);                            \
      acc = MFMA16(af[0][tq], b2##S, acc, 0, 0, 0);                            \
      acc = MFMA16(af[1][tq], b1##S, acc, 0, 0, 0);                            \
      acc = MFMA16(af[1][tq], b2##S, acc, 0, 0, 0);                            \
      acc = MFMA16(af[0][tq], b3##S, acc, 0, 0, 0);                            \
      acc = MFMA16(af[2][tq], b1##S, acc, 0, 0, 0);                            \
      _Pragma("unroll") for (int i = 0; i < 4; ++i) {                          \
        float d = fmaf(-2.f, acc[i], cq##S);                                   \
        if (d < bd[tq][i]) { bd[tq][i] = d; bi[tq][i] = (CT)*16 + cl; }        \
      }                                                                        \
    }                                                                          \
  }

  short8 b1A, b2A, b3A, b1B, b2B, b3B;
  float cqA, cqB;
  LOADB(A, 0)
  LOADB(B, 1)
#pragma unroll 1
  for (int ct = 0; ct < 32; ct += 2) {
    COMPUTE(A, ct)
    LOADB(A, (ct + 2) & 31)  // distance-2 prefetch; wrap: in-bounds, unused
    COMPUTE(B, ct + 1)
    LOADB(B, (ct + 3) & 31)
  }
#undef LOADB
#undef COMPUTE

#pragma unroll
  for (int tq = 0; tq < 4; ++tq)
#pragma unroll
    for (int i = 0; i < 4; ++i)
#pragma unroll
      for (int m = 1; m < 16; m <<= 1) {
        float od = __shfl_xor(bd[tq][i], m, 64);
        int ob = __shfl_xor(bi[tq][i], m, 64);
        if (od < bd[tq][i] || (od == bd[tq][i] && ob < bi[tq][i])) {
          bd[tq][i] = od;
          bi[tq][i] = ob;
        }
      }
  if (cl == 0) {
#pragma unroll
    for (int tq = 0; tq < 4; ++tq)
#pragma unroll
      for (int i = 0; i < 4; ++i) {
        int tokl = w * 64 + tq * 16 + (l >> 4) * 4 + i;
        sBi[tokl] = bi[tq][i];
        sBd[tokl] = bd[tq][i];
      }
  }
  __syncthreads();

  idxout[t0 + tid] = (float)sBi[tid];
  float loss = sBd[tid] + sFsq[tid];  // ||q-f||^2 = csq - 2 f.c + ||f||^2
#pragma unroll
  for (int off = 32; off > 0; off >>= 1) loss += __shfl_down(loss, off, 64);
  if (l == 0) sred[w] = loss;
  __syncthreads();
  if (tid == 0) partial[blk] = (sred[0] + sred[1]) + (sred[2] + sred[3]);
}

// ---------------- Kernel F: finalize commit loss (512 partials) ----------------
__global__ __launch_bounds__(256) void k_loss(const float* __restrict__ partial,
                                              float* __restrict__ lossout) {
  __shared__ float sred[4];
  int tid = threadIdx.x;
  float v = partial[tid] + partial[tid + 256];
#pragma unroll
  for (int off = 32; off > 0; off >>= 1) v += __shfl_down(v, off, 64);
  if ((tid & 63) == 0) sred[tid >> 6] = v;
  __syncthreads();
  if (tid == 0)
    lossout[0] = ((sred[0] + sred[1]) + (sred[2] + sred[3])) * (1.0f / 4194304.0f);
}

// ---------------- Kernel D: up2 + conv (32->16) + gelu via split MFMA ----------
// Implicit GEMM, phase-packed B: D[32 qpos_x][col=(b2,oc)] per phase-pair pp
// (pp = output row-phase a). 9 A-positions (ry,cx) x 2 k-halves; invalid
// (tap,phase) B entries are zero (padded in wfd1) and all-zero pp skipped.
// Block: q-tile 8 rows x 32 cols; wave = 2 row-strips; absrow loop shares
// A-frags across strips (72 b128/wave ~ MFMA-pipe parity). Staging: idx-gather
// of pre-split codebook rows from cbs (quantized h2 == cb[idx] bit-exact),
// no fp32 read, no SPLIT3. Weights: wfd1 lane-ordered, 1KB coalesced loads.
__global__ __launch_bounds__(256, 2) void k_dec1(const float* __restrict__ idxf,
                                                 const unsigned short* __restrict__ cbs,
                                                 const unsigned short* __restrict__ wfd1,
                                                 const float* __restrict__ bias,
                                                 float* __restrict__ o) {
  __shared__ __align__(16) unsigned short sA[3 * 12240];  // [part][10][34][36]
  __shared__ int sIdx[340];
  const int PP = 12240;
  int tid = threadIdx.x;
  int b = blockIdx.y;
  int qx0 = (blockIdx.x & 1) * 32, qy0 = (blockIdx.x >> 1) * 8;
  const float* ib = idxf + (size_t)b * 4096;
  for (int i = tid; i < 340; i += 256) {
    int yy = i / 34, xx = i % 34;
    int y = qy0 - 1 + yy, x = qx0 - 1 + xx;
    sIdx[i] = ((unsigned)y < 64u && (unsigned)x < 64u) ? (int)ib[y * 64 + x] : -1;
  }
  __syncthreads();
  for (int i = tid; i < 4080; i += 256) {  // 340 pos x (3 part x 4 g)
    int pos = i / 12, sub = i % 12, part = sub >> 2, g = sub & 3;
    int idx = sIdx[pos];
    short8 v = {0, 0, 0, 0, 0, 0, 0, 0};
    if (idx >= 0) v = *(const short8*)(cbs + ((part << 9) + idx) * 32 + g * 8);
    *(short8*)(sA + part * PP + pos * 36 + g * 8) = v;
  }
  __syncthreads();

  int l = tid & 63, w = tid >> 6;
  int xl = l & 31, hi = l >> 5;
  f32x16 acc[2][2];  // [strip][pp] - constant-indexed under full unroll
#pragma unroll
  for (int s = 0; s < 2; ++s)
#pragma unroll
    for (int p2 = 0; p2 < 2; ++p2)
#pragma unroll
      for (int r = 0; r < 16; ++r) acc[s][p2][r] = 0.f;

#pragma unroll
  for (int cx = 0; cx < 3; ++cx) {
    // B-frags for this cx: valid (ry,pp) combos q: (0,0),(1,0),(1,1),(2,1); q=ry+pp
    short8 Bf[4][2][3];
#pragma unroll
    for (int q = 0; q < 4; ++q) {
      int r3 = (q == 0) ? 0 : (q == 3) ? 2 : 1;
      int pq = (q >= 2) ? 1 : 0;
#pragma unroll
      for (int kh = 0; kh < 2; ++kh)
#pragma unroll
        for (int pt = 0; pt < 3; ++pt) {
          int slot = cx * 36 + r3 * 12 + kh * 6 + pq * 3 + pt;
          Bf[q][kh][pt] = *(const short8*)(wfd1 + (size_t)slot * 512 + l * 8);
        }
    }
#pragma unroll
    for (int ar = 0; ar < 4; ++ar) {
#pragma unroll
      for (int kh = 0; kh < 2; ++kh) {
        const unsigned short* ap =
            sA + ((2 * w + ar) * 34 + xl + cx) * 36 + kh * 16 + hi * 8;
        short8 a1 = *(const short8*)(ap);
        short8 a2 = *(const short8*)(ap + PP);
        short8 a3 = *(const short8*)(ap + 2 * PP);
#pragma unroll
        for (int s = 0; s < 2; ++s) {
          int ry = ar - s;
          if (ry < 0 || ry > 2) continue;  // compile-time folded
#pragma unroll
          for (int p2 = 0; p2 < 2; ++p2) {
            if ((ry == 0 && p2 == 1) || (ry == 2 && p2 == 0)) continue;
            int q = ry + p2;
            f32x16 t = acc[s][p2];
            t = MFMA32(a1, Bf[q][kh][0], t, 0, 0, 0);
            t = MFMA32(a1, Bf[q][kh][1], t, 0, 0, 0);
            t = MFMA32(a2, Bf[q][kh][0], t, 0, 0, 0);
            t = MFMA32(a2, Bf[q][kh][1], t, 0, 0, 0);
            t = MFMA32(a1, Bf[q][kh][2], t, 0, 0, 0);
            t = MFMA32(a3, Bf[q][kh][0], t, 0, 0, 0);
            acc[s][p2] = t;
          }
        }
      }
    }
  }

  // epilogue: D row = qpos_x = (reg&3)+8*(reg>>2)+4*hi; col c=l&31 -> b2,oc.
  float bv = bias[l & 15];
  int b2 = (l >> 4) & 1;
  float* ob = o + (size_t)b * 262144 + (size_t)(l & 15) * 16384 + (qx0 << 1) + b2;
#pragma unroll
  for (int s = 0; s < 2; ++s) {
    int qy = qy0 + 2 * w + s;
#pragma unroll
    for (int p2 = 0; p2 < 2; ++p2) {
      int Y = 2 * qy + p2;
      float* op = ob + Y * 128;
#pragma unroll
      for (int reg = 0; reg < 16; ++reg) {
        int rowval = (reg & 3) + 8 * (reg >> 2) + 4 * hi;
        op[2 * rowval] = GELU(acc[s][p2][reg] + bv);
      }
    }
  }
}

// ---------------- Kernel E: up2 + conv (16->1) + clip, phase-folded ------------
__global__ __launch_bounds__(256) void k_dec2(const float* __restrict__ d1,
                                              const float* __restrict__ fwd2,
                                              const float* __restrict__ bias,
                                              float* __restrict__ out) {
  __shared__ float st[16 * 360];  // [ic][18 rows][20]
  int tid = threadIdx.x;
  int b = blockIdx.y;
  int R0 = (blockIdx.x >> 3) * 16, C0 = (blockIdx.x & 7) * 16;
  const float* ip = d1 + (size_t)b * 262144;
  for (int i = tid; i < 5184; i += 256) {  // 16 ic x 18 x 18
    int ic = i / 324, rr = (i % 324) / 18, cc = i % 18;
    int r = R0 - 1 + rr, c = C0 - 1 + cc;
    st[ic * 360 + rr * 20 + cc] =
        ((unsigned)r < 128u && (unsigned)c < 128u) ? ip[ic * 16384 + r * 128 + c] : 0.f;
  }
  __syncthreads();
  int lane = tid & 63, wid = tid >> 6;
  int qy = wid >> 1, qx = wid & 1;
  int ty = qy * 8 + (lane >> 3), tx = qx * 8 + (lane & 7);
  float acc[4] = {0.f, 0.f, 0.f, 0.f};
#pragma unroll 1
  for (int ic = 0; ic < 16; ++ic) {
    const float* t = st + ic * 360 + ty * 20 + tx;
    float i3[3][3];
#pragma unroll
    for (int dy = 0; dy < 3; ++dy)
#pragma unroll
      for (int dx = 0; dx < 3; ++dx) i3[dy][dx] = t[dy * 20 + dx];
    const float* wp = fwd2 + ic * 16;  // scalar loads
#pragma unroll
    for (int p = 0; p < 4; ++p) {
      int a = p >> 1, b2 = p & 1;
#pragma unroll
      for (int tp = 0; tp < 4; ++tp) {
        int dy = tp >> 1, dx = tp & 1;
        acc[p] = fmaf(i3[a + dy][b2 + dx], wp[p * 4 + tp], acc[p]);
      }
    }
  }
  float bv = bias[0];
  int Y = 2 * (R0 + ty), X = 2 * (C0 + tx);
  float* op = out + (size_t)b * 65536 + Y * 256 + X;
  float2 r0v, r1v;
  r0v.x = fminf(1.0f, fmaxf(-1.0f, acc[0] + bv));
  r0v.y = fminf(1.0f, fmaxf(-1.0f, acc[1] + bv));
  r1v.x = fminf(1.0f, fmaxf(-1.0f, acc[2] + bv));
  r1v.y = fminf(1.0f, fmaxf(-1.0f, acc[3] + bv));
  *(float2*)op = r0v;
  *(float2*)(op + 256) = r1v;
}

extern "C" void kernel_launch(void* const* d_in, const int* in_sizes, int n_in,
                              void* d_out, int out_size, void* d_ws, size_t ws_size,
                              hipStream_t stream) {
  const float* x   = (const float*)d_in[0];
  const float* e1w = (const float*)d_in[1];
  const float* e1b = (const float*)d_in[2];
  const float* e2w = (const float*)d_in[3];
  const float* e2b = (const float*)d_in[4];
  const float* cb  = (const float*)d_in[5];
  const float* d1w = (const float*)d_in[6];
  const float* d1b = (const float*)d_in[7];
  const float* d2w = (const float*)d_in[8];
  const float* d2b = (const float*)d_in[9];

  float* out = (float*)d_out;
  float* y       = out;                       // [32,1,256,256] = 2097152
  float* idxout  = out + 2097152;             // [32,64,64]     = 131072 (as float)
  float* lossout = out + 2097152 + 131072;    // scalar

  float* ws = (float*)d_ws;
  float* h1      = ws;                        // h1t[32][128][128][16] = 8388608
  float* h2      = ws + 8388608;              // [32,32,64,64]   = 4194304
  float* partial = ws + 12582912;             // 512 floats
  float* fwd2    = ws + 12596224;             // 256
  float* d1o     = h1;                        // dec1 output reuses h1 (after vq)

  // Scratch in the y-region of out (written by k_fold, consumed before k_dec2
  // overwrites all of y): cbs 24576f, csqg 512f, wfrag 6912f, wfd1 27648f.
  unsigned short* cbs = (unsigned short*)out;              // 49152 bf16
  float* csqg = out + 24576;                               // 512
  unsigned short* wfrag = (unsigned short*)(out + 25088);  // 13824 bf16
  unsigned short* wfd1 = (unsigned short*)(out + 32000);   // 55296 bf16

  k_fold<<<dim3(337), 256, 0, stream>>>(e2w, d1w, d2w, cb, fwd2, cbs, csqg, wfrag, wfd1);
  k_enc1<<<dim3(2048), 256, 0, stream>>>(x, e1w, e1b, h1);
  k_enc2<<<dim3(64, 32), 256, 0, stream>>>(h1, wfrag, e2b, h2);
  k_vq<<<dim3(512), 256, 0, stream>>>(h2, cbs, csqg, idxout, partial);
  k_loss<<<dim3(1), 256, 0, stream>>>(partial, lossout);
  k_dec1<<<dim3(16, 32), 256, 0, stream>>>(idxout, cbs, wfd1, d1b, d1o);
  k_dec2<<<dim3(64, 32), 256, 0, stream>>>(d1o, fwd2, d2b, y);
}

// Round 12
// 227.365 us; speedup vs baseline: 1.5786x; 1.0666x over previous
//
#include <hip/hip_runtime.h>
#include <math.h>

#define GELU(v) (0.5f * (v) * (1.0f + erff((v)*0.70710678118654752440f)))

typedef __attribute__((ext_vector_type(8))) short short8;
typedef __attribute__((ext_vector_type(4))) float f32x4;
typedef __attribute__((ext_vector_type(16))) float f32x16;
#define MFMA16 __builtin_amdgcn_mfma_f32_16x16x32_bf16
#define MFMA32 __builtin_amdgcn_mfma_f32_32x32x16_bf16

// Exact 3-way bf16 split of fp32 (24 = 3x8 mantissa bits, truncation):
// v == p1 + p2 + p3 exactly (each pi representable in bf16).
#define SPLIT3(V, U1, U2, U3)                                                  \
  unsigned U1 = __float_as_uint(V) & 0xFFFF0000u;                              \
  float _r1 = (V)-__uint_as_float(U1);                                         \
  unsigned U2 = __float_as_uint(_r1) & 0xFFFF0000u;                            \
  float _r2 = _r1 - __uint_as_float(U2);                                       \
  unsigned U3 = __float_as_uint(_r2) & 0xFFFF0000u;

// ---------------- Setup: fold weights + split codebook/enc2/dec1 weights -------
__global__ __launch_bounds__(256) void k_fold(const float* __restrict__ e2w,
                                              const float* __restrict__ d1w,
                                              const float* __restrict__ d2w,
                                              const float* __restrict__ cb,
                                              float* __restrict__ fwd2,
                                              unsigned short* __restrict__ cbs,
                                              float* __restrict__ csqg,
                                              unsigned short* __restrict__ wfrag,
                                              unsigned short* __restrict__ wfd1) {
  int i = blockIdx.x * 256 + threadIdx.x;
  if (i < 256) {
    int j = i;
    int pt = j & 15, ic = j >> 4;
    int a = pt >> 3, b2 = (pt >> 2) & 1, dy = (pt >> 1) & 1, dx = pt & 1;
    const float* wsrc = d2w + ic * 9;
    float s = 0.f;
    for (int ky = 0; ky < 3; ++ky) {
      int rm = (a == 0) ? (ky == 0 ? 0 : 1) : (ky == 2 ? 1 : 0);
      if (rm != dy) continue;
      for (int kx = 0; kx < 3; ++kx) {
        int cm = (b2 == 0) ? (kx == 0 ? 0 : 1) : (kx == 2 ? 1 : 0);
        if (cm == dx) s += wsrc[ky * 3 + kx];
      }
    }
    fwd2[j] = s;
  } else if (i < 16640) {
    int j = i - 256;  // [0, 16384): code = j>>5, ch = j&31
    float v = cb[j];
    SPLIT3(v, u1, u2, u3)
    cbs[j] = (unsigned short)(u1 >> 16);
    cbs[16384 + j] = (unsigned short)(u2 >> 16);
    cbs[32768 + j] = (unsigned short)(u3 >> 16);
  } else if (i < 17152) {
    int c = i - 16640;
    const float* row = cb + (size_t)c * 32;
    float s = 0.f;
#pragma unroll
    for (int d = 0; d < 32; ++d) s = fmaf(row[d], row[d], s);
    csqg[c] = s;
  } else if (i < 30976) {
    int j = i - 17152;  // [0, 13824)
    int p = j / 4608, rem = j - p * 4608;
    int t = rem >> 9, l2 = (rem >> 3) & 63, jj = rem & 7;
    float v = e2w[((l2 & 31) * 16 + ((l2 >> 5) * 8 + jj)) * 9 + t];
    SPLIT3(v, u1, u2, u3)
    unsigned short r = (p == 0)   ? (unsigned short)(u1 >> 16)
                       : (p == 1) ? (unsigned short)(u2 >> 16)
                                  : (unsigned short)(u3 >> 16);
    wfrag[j] = r;
  } else if (i < 86272) {
    int j = i - 30976;  // [0, 55296)
    int slot = j >> 9, l2 = (j >> 3) & 63, jj = j & 7;
    int cx = slot / 36, rem = slot % 36;
    int r3 = rem / 12, rem2 = rem % 12;
    int kh = rem2 / 6, rem3 = rem2 % 6;
    int pp = rem3 / 3, part = rem3 % 3;
    int c = l2 & 31, hi = l2 >> 5;
    int oc = c & 15, b2 = c >> 4;
    int ic = kh * 16 + hi * 8 + jj;
    int dy = r3 - pp, dx = cx - b2;
    float s = 0.f;
    if ((unsigned)dy < 2u && (unsigned)dx < 2u) {
      const float* wsrc = d1w + (oc * 32 + ic) * 9;
      for (int ky = 0; ky < 3; ++ky) {
        int rm = (pp == 0) ? (ky == 0 ? 0 : 1) : (ky == 2 ? 1 : 0);
        if (rm != dy) continue;
        for (int kx = 0; kx < 3; ++kx) {
          int cm = (b2 == 0) ? (kx == 0 ? 0 : 1) : (kx == 2 ? 1 : 0);
          if (cm == dx) s += wsrc[ky * 3 + kx];
        }
      }
    }
    SPLIT3(s, u1, u2, u3)
    unsigned short r = (part == 0)   ? (unsigned short)(u1 >> 16)
                       : (part == 1) ? (unsigned short)(u2 >> 16)
                                     : (unsigned short)(u3 >> 16);
    wfd1[j] = r;
  }
}

// ---------------- Kernel A: conv1 (1->16) + maxpool2 + gelu --------------------
// XCD-slab mapping: block n -> ysl=n&7 (XCD tag under %8 dispatch), b=(n>>3)&31,
// k=n>>8; block writes h1 rows ysl*16+2k..+2k+1 of batch b -> each 16-row slab
// of each batch is written entirely by one XCD class (read-locality for enc2).
__global__ __launch_bounds__(256) void k_enc1(const float* __restrict__ x,
                                              const float* __restrict__ w,
                                              const float* __restrict__ bias,
                                              float* __restrict__ h1) {
  int n = blockIdx.x;
  int ysl = n & 7, m = n >> 3;
  int b = m & 31, k = m >> 5;
  int yy = ysl * 16 + k * 2 + (threadIdx.x >> 7);
  int xx = threadIdx.x & 127;
  const float* xp = x + (size_t)b * 65536;
  int r0 = 2 * yy - 1, c0 = 2 * xx - 1;
  float in[4][4];
#pragma unroll
  for (int i = 0; i < 4; ++i) {
    int r = r0 + i;
    bool rv = (unsigned)r < 256u;
#pragma unroll
    for (int j = 0; j < 4; ++j) {
      int c = c0 + j;
      in[i][j] = (rv && (unsigned)c < 256u) ? xp[r * 256 + c] : 0.0f;
    }
  }
  float vout[16];
#pragma unroll
  for (int oc = 0; oc < 16; ++oc) {
    const float* wp = w + oc * 9;  // uniform -> s_load
    float s00 = 0.f, s01 = 0.f, s10 = 0.f, s11 = 0.f;
#pragma unroll
    for (int ky = 0; ky < 3; ++ky)
#pragma unroll
      for (int kx = 0; kx < 3; ++kx) {
        float wv = wp[ky * 3 + kx];
        s00 = fmaf(in[ky][kx], wv, s00);
        s01 = fmaf(in[ky][kx + 1], wv, s01);
        s10 = fmaf(in[ky + 1][kx], wv, s10);
        s11 = fmaf(in[ky + 1][kx + 1], wv, s11);
      }
    float mm = fmaxf(fmaxf(s00, s01), fmaxf(s10, s11)) + bias[oc];
    vout[oc] = GELU(mm);
  }
  float* op = h1 + (size_t)b * 262144 + ((size_t)yy * 128 + xx) * 16;
#pragma unroll
  for (int q = 0; q < 4; ++q) {
    float4 vq;
    vq.x = vout[4 * q + 0]; vq.y = vout[4 * q + 1];
    vq.z = vout[4 * q + 2]; vq.w = vout[4 * q + 3];
    *(float4*)(op + 4 * q) = vq;
  }
}

// ---------------- Kernel B: conv2 (16->32) + maxpool2 via split MFMA -----------
// r12: (a) granule staging — thread = 8ch granule-group: 2x float4 global read,
// 8 SPLIT3, 3x ds_write_b128 (3 iters/thread, loads independent & early-issued;
// was 21 iters of scalar load+split+b16 writes = serialized latency exposure).
// (b) XCD-matched 1-D grid: n&7 selects ty pair so the tile's h1 slab was
// written by the same XCD class (enc1 mapping above) -> local-L2 hits.
__global__ __launch_bounds__(256) void k_enc2(const float* __restrict__ h1,
                                              const unsigned short* __restrict__ wfrag,
                                              const float* __restrict__ bias,
                                              float* __restrict__ h2) {
  __shared__ __align__(16) unsigned short sA[3 * 2 * 10 * 34 * 8];  // 32640 B
  const int PP = 2 * 10 * 34 * 8;
  int tid = threadIdx.x;
  int n = blockIdx.x;
  int xcd = n & 7, m = n >> 3;
  int ty = xcd * 2 + (m & 1);
  int q0 = m >> 1;
  int b = q0 >> 2, xt = q0 & 3;
  int X0 = xt * 32, Y0 = ty * 8;
  const float* ip = h1 + (size_t)b * 262144;
  for (int g = tid; g < 680; g += 256) {  // pos(340) x ich(2) granule-groups
    int pos = g >> 1, ich = g & 1;
    int yy = pos / 34, xx = pos - yy * 34;
    int y = Y0 - 1 + yy, xg = X0 - 1 + xx;
    float4 v0 = {0.f, 0.f, 0.f, 0.f}, v1 = {0.f, 0.f, 0.f, 0.f};
    if ((unsigned)y < 128u && (unsigned)xg < 128u) {
      const float* sp = ip + ((size_t)y * 128 + xg) * 16 + ich * 8;
      v0 = *(const float4*)(sp);
      v1 = *(const float4*)(sp + 4);
    }
    float vv[8] = {v0.x, v0.y, v0.z, v0.w, v1.x, v1.y, v1.z, v1.w};
    short8 p1, p2, p3;
#pragma unroll
    for (int e = 0; e < 8; ++e) {
      SPLIT3(vv[e], u1, u2, u3)
      p1[e] = (short)(u1 >> 16);
      p2[e] = (short)(u2 >> 16);
      p3[e] = (short)(u3 >> 16);
    }
    int si = ((ich * 10 + yy) * 34 + xx) * 8;
    *(short8*)(sA + si) = p1;
    *(short8*)(sA + PP + si) = p2;
    *(short8*)(sA + 2 * PP + si) = p3;
  }
  __syncthreads();

  int l = tid & 63, w = tid >> 6;
  int xl = l & 31, ich = l >> 5;
  f32x16 acc0[2], acc1[2];
#pragma unroll
  for (int s = 0; s < 2; ++s)
#pragma unroll
    for (int r = 0; r < 16; ++r) { acc0[s][r] = 0.f; acc1[s][r] = 0.f; }

#pragma unroll
  for (int t = 0; t < 9; ++t) {
    int dy = t / 3, dx = t % 3;
    int s = t & 1;
    const unsigned short* wb = wfrag + t * 512 + l * 8;
    short8 bf1 = *(const short8*)(wb);
    short8 bf2 = *(const short8*)(wb + 4608);
    short8 bf3 = *(const short8*)(wb + 9216);
    int g0 = ((ich * 10) + (2 * w + dy)) * 34 + xl + dx;
    const unsigned short* a0p = sA + g0 * 8;
    short8 a01 = *(const short8*)(a0p);
    short8 a02 = *(const short8*)(a0p + PP);
    short8 a03 = *(const short8*)(a0p + 2 * PP);
    const unsigned short* a1p = a0p + 34 * 8;
    short8 a11 = *(const short8*)(a1p);
    short8 a12 = *(const short8*)(a1p + PP);
    short8 a13 = *(const short8*)(a1p + 2 * PP);
    acc0[s] = MFMA32(a01, bf1, acc0[s], 0, 0, 0);
    acc0[s] = MFMA32(a01, bf2, acc0[s], 0, 0, 0);
    acc0[s] = MFMA32(a02, bf1, acc0[s], 0, 0, 0);
    acc0[s] = MFMA32(a02, bf2, acc0[s], 0, 0, 0);
    acc0[s] = MFMA32(a01, bf3, acc0[s], 0, 0, 0);
    acc0[s] = MFMA32(a03, bf1, acc0[s], 0, 0, 0);
    acc1[s] = MFMA32(a11, bf1, acc1[s], 0, 0, 0);
    acc1[s] = MFMA32(a11, bf2, acc1[s], 0, 0, 0);
    acc1[s] = MFMA32(a12, bf1, acc1[s], 0, 0, 0);
    acc1[s] = MFMA32(a12, bf2, acc1[s], 0, 0, 0);
    acc1[s] = MFMA32(a11, bf3, acc1[s], 0, 0, 0);
    acc1[s] = MFMA32(a13, bf1, acc1[s], 0, 0, 0);
  }

  float bv = bias[l & 31];
  int ypool = (Y0 >> 1) + w;
  float* op = h2 + (size_t)b * 131072 + (size_t)(l & 31) * 4096 + ypool * 64 + (X0 >> 1);
#pragma unroll
  for (int k = 0; k < 8; ++k) {
    float e0 = (acc0[0][2 * k] + acc0[1][2 * k]);
    float o0 = (acc0[0][2 * k + 1] + acc0[1][2 * k + 1]);
    float e1 = (acc1[0][2 * k] + acc1[1][2 * k]);
    float o1 = (acc1[0][2 * k + 1] + acc1[1][2 * k + 1]);
    float mm = fmaxf(fmaxf(e0, o0), fmaxf(e1, o1)) + bv;
    int row = ((2 * k) & 3) + 8 * ((2 * k) >> 2) + 4 * ich;
    op[row >> 1] = mm;
  }
}

// ---------------- Kernel C: VQ via exact-split bf16 MFMA (r11 structure) -------
__global__ __launch_bounds__(256) void k_vq(const float* __restrict__ h2,
                                            const unsigned short* __restrict__ cbs,
                                            const float* __restrict__ csqg,
                                            float* __restrict__ idxout,
                                            float* __restrict__ partial) {
  __shared__ __align__(16) unsigned short sA[3 * 256 * 40];  // [part][tok][40]
  __shared__ float sFsq[256];
  __shared__ float sBd[256];
  __shared__ int sBi[256];
  __shared__ float sred[4];
  int tid = threadIdx.x;
  int blk = blockIdx.x;
  int t0 = blk * 256;
  size_t abase = (size_t)(t0 >> 12) * 131072 + (t0 & 4095);

  {
    const float* src = h2 + abase + tid;
    float fsq = 0.f;
#pragma unroll
    for (int g = 0; g < 4; ++g) {
      short8 p1, p2, p3;
#pragma unroll
      for (int e = 0; e < 8; ++e) {
        float v = src[(g * 8 + e) * 4096];
        fsq = fmaf(v, v, fsq);
        SPLIT3(v, u1, u2, u3)
        p1[e] = (short)(u1 >> 16);
        p2[e] = (short)(u2 >> 16);
        p3[e] = (short)(u3 >> 16);
      }
      *(short8*)(sA + (0 * 256 + tid) * 40 + g * 8) = p1;
      *(short8*)(sA + (1 * 256 + tid) * 40 + g * 8) = p2;
      *(short8*)(sA + (2 * 256 + tid) * 40 + g * 8) = p3;
    }
    sFsq[tid] = fsq;
  }
  __syncthreads();

  int l = tid & 63, w = tid >> 6;
  int cl = l & 15, k0 = (l >> 4) * 8;
  short8 af[3][4];
#pragma unroll
  for (int p = 0; p < 3; ++p)
#pragma unroll
    for (int tq = 0; tq < 4; ++tq) {
      int tok = w * 64 + tq * 16 + cl;
      af[p][tq] = *(const short8*)(sA + (p * 256 + tok) * 40 + k0);
    }

  float bd[4][4];
  int bi[4][4];
#pragma unroll
  for (int a = 0; a < 4; ++a)
#pragma unroll
    for (int b = 0; b < 4; ++b) { bd[a][b] = 3.4e38f; bi[a][b] = 0; }

#define LOADB(S, CT)                                                           \
  {                                                                            \
    int col = (CT)*16 + cl;                                                    \
    b1##S = *(const short8*)(cbs + (0 * 512 + col) * 32 + k0);                 \
    b2##S = *(const short8*)(cbs + (1 * 512 + col) * 32 + k0);                 \
    b3##S = *(const short8*)(cbs + (2 * 512 + col) * 32 + k0);                 \
    cq##S = csqg[col];                                                         \
  }
#define COMPUTE(S, CT)                                                         \
  {                                                                            \
    _Pragma("unroll") for (int tq = 0; tq < 4; ++tq) {                         \
      f32x4 acc = {0.f, 0.f, 0.f, 0.f};                                        \
      acc = MFMA16(af[0][tq], b1##S, acc, 0, 0, 0);                            \
      acc = MFMA16(af[0][tq], b2##S, acc, 0, 0, 0);                            \
      acc = MFMA16(af[1][tq], b1##S, acc, 0, 0, 0);                            \
      acc = MFMA16(af[1][tq], b2##S, acc, 0, 0, 0);                            \
      acc = MFMA16(af[0][tq], b3##S, acc, 0, 0, 0);                            \
      acc = MFMA16(af[2][tq], b1##S, acc, 0, 0, 0);                            \
      _Pragma("unroll") for (int i = 0; i < 4; ++i) {                          \
        float d = fmaf(-2.f, acc[i], cq##S);                                   \
        if (d < bd[tq][i]) { bd[tq][i] = d; bi[tq][i] = (CT)*16 + cl; }        \
      }                                                                        \
    }                                                                          \
  }

  short8 b1A, b2A, b3A, b1B, b2B, b3B;
  float cqA, cqB;
  LOADB(A, 0)
  LOADB(B, 1)
#pragma unroll 1
  for (int ct = 0; ct < 32; ct += 2) {
    COMPUTE(A, ct)
    LOADB(A, (ct + 2) & 31)  // distance-2 prefetch; wrap: in-bounds, unused
    COMPUTE(B, ct + 1)
    LOADB(B, (ct + 3) & 31)
  }
#undef LOADB
#undef COMPUTE

#pragma unroll
  for (int tq = 0; tq < 4; ++tq)
#pragma unroll
    for (int i = 0; i < 4; ++i)
#pragma unroll
      for (int m = 1; m < 16; m <<= 1) {
        float od = __shfl_xor(bd[tq][i], m, 64);
        int ob = __shfl_xor(bi[tq][i], m, 64);
        if (od < bd[tq][i] || (od == bd[tq][i] && ob < bi[tq][i])) {
          bd[tq][i] = od;
          bi[tq][i] = ob;
        }
      }
  if (cl == 0) {
#pragma unroll
    for (int tq = 0; tq < 4; ++tq)
#pragma unroll
      for (int i = 0; i < 4; ++i) {
        int tokl = w * 64 + tq * 16 + (l >> 4) * 4 + i;
        sBi[tokl] = bi[tq][i];
        sBd[tokl] = bd[tq][i];
      }
  }
  __syncthreads();

  idxout[t0 + tid] = (float)sBi[tid];
  float loss = sBd[tid] + sFsq[tid];  // ||q-f||^2 = csq - 2 f.c + ||f||^2
#pragma unroll
  for (int off = 32; off > 0; off >>= 1) loss += __shfl_down(loss, off, 64);
  if (l == 0) sred[w] = loss;
  __syncthreads();
  if (tid == 0) partial[blk] = (sred[0] + sred[1]) + (sred[2] + sred[3]);
}

// ---------------- Kernel F: finalize commit loss (512 partials) ----------------
__global__ __launch_bounds__(256) void k_loss(const float* __restrict__ partial,
                                              float* __restrict__ lossout) {
  __shared__ float sred[4];
  int tid = threadIdx.x;
  float v = partial[tid] + partial[tid + 256];
#pragma unroll
  for (int off = 32; off > 0; off >>= 1) v += __shfl_down(v, off, 64);
  if ((tid & 63) == 0) sred[tid >> 6] = v;
  __syncthreads();
  if (tid == 0)
    lossout[0] = ((sred[0] + sred[1]) + (sred[2] + sred[3])) * (1.0f / 4194304.0f);
}

// ---------------- Kernel D: up2 + conv (32->16) + gelu via split MFMA ----------
// (r11-verified.)
__global__ __launch_bounds__(256, 2) void k_dec1(const float* __restrict__ idxf,
                                                 const unsigned short* __restrict__ cbs,
                                                 const unsigned short* __restrict__ wfd1,
                                                 const float* __restrict__ bias,
                                                 float* __restrict__ o) {
  __shared__ __align__(16) unsigned short sA[3 * 12240];  // [part][10][34][36]
  __shared__ int sIdx[340];
  const int PP = 12240;
  int tid = threadIdx.x;
  int b = blockIdx.y;
  int qx0 = (blockIdx.x & 1) * 32, qy0 = (blockIdx.x >> 1) * 8;
  const float* ib = idxf + (size_t)b * 4096;
  for (int i = tid; i < 340; i += 256) {
    int yy = i / 34, xx = i % 34;
    int y = qy0 - 1 + yy, x = qx0 - 1 + xx;
    sIdx[i] = ((unsigned)y < 64u && (unsigned)x < 64u) ? (int)ib[y * 64 + x] : -1;
  }
  __syncthreads();
  for (int i = tid; i < 4080; i += 256) {  // 340 pos x (3 part x 4 g)
    int pos = i / 12, sub = i % 12, part = sub >> 2, g = sub & 3;
    int idx = sIdx[pos];
    short8 v = {0, 0, 0, 0, 0, 0, 0, 0};
    if (idx >= 0) v = *(const short8*)(cbs + ((part << 9) + idx) * 32 + g * 8);
    *(short8*)(sA + part * PP + pos * 36 + g * 8) = v;
  }
  __syncthreads();

  int l = tid & 63, w = tid >> 6;
  int xl = l & 31, hi = l >> 5;
  f32x16 acc[2][2];
#pragma unroll
  for (int s = 0; s < 2; ++s)
#pragma unroll
    for (int p2 = 0; p2 < 2; ++p2)
#pragma unroll
      for (int r = 0; r < 16; ++r) acc[s][p2][r] = 0.f;

#pragma unroll
  for (int cx = 0; cx < 3; ++cx) {
    short8 Bf[4][2][3];
#pragma unroll
    for (int q = 0; q < 4; ++q) {
      int r3 = (q == 0) ? 0 : (q == 3) ? 2 : 1;
      int pq = (q >= 2) ? 1 : 0;
#pragma unroll
      for (int kh = 0; kh < 2; ++kh)
#pragma unroll
        for (int pt = 0; pt < 3; ++pt) {
          int slot = cx * 36 + r3 * 12 + kh * 6 + pq * 3 + pt;
          Bf[q][kh][pt] = *(const short8*)(wfd1 + (size_t)slot * 512 + l * 8);
        }
    }
#pragma unroll
    for (int ar = 0; ar < 4; ++ar) {
#pragma unroll
      for (int kh = 0; kh < 2; ++kh) {
        const unsigned short* ap =
            sA + ((2 * w + ar) * 34 + xl + cx) * 36 + kh * 16 + hi * 8;
        short8 a1 = *(const short8*)(ap);
        short8 a2 = *(const short8*)(ap + PP);
        short8 a3 = *(const short8*)(ap + 2 * PP);
#pragma unroll
        for (int s = 0; s < 2; ++s) {
          int ry = ar - s;
          if (ry < 0 || ry > 2) continue;
#pragma unroll
          for (int p2 = 0; p2 < 2; ++p2) {
            if ((ry == 0 && p2 == 1) || (ry == 2 && p2 == 0)) continue;
            int q = ry + p2;
            f32x16 t = acc[s][p2];
            t = MFMA32(a1, Bf[q][kh][0], t, 0, 0, 0);
            t = MFMA32(a1, Bf[q][kh][1], t, 0, 0, 0);
            t = MFMA32(a2, Bf[q][kh][0], t, 0, 0, 0);
            t = MFMA32(a2, Bf[q][kh][1], t, 0, 0, 0);
            t = MFMA32(a1, Bf[q][kh][2], t, 0, 0, 0);
            t = MFMA32(a3, Bf[q][kh][0], t, 0, 0, 0);
            acc[s][p2] = t;
          }
        }
      }
    }
  }

  float bv = bias[l & 15];
  int b2 = (l >> 4) & 1;
  float* ob = o + (size_t)b * 262144 + (size_t)(l & 15) * 16384 + (qx0 << 1) + b2;
#pragma unroll
  for (int s = 0; s < 2; ++s) {
    int qy = qy0 + 2 * w + s;
#pragma unroll
    for (int p2 = 0; p2 < 2; ++p2) {
      int Y = 2 * qy + p2;
      float* op = ob + Y * 128;
#pragma unroll
      for (int reg = 0; reg < 16; ++reg) {
        int rowval = (reg & 3) + 8 * (reg >> 2) + 4 * hi;
        op[2 * rowval] = GELU(acc[s][p2][reg] + bv);
      }
    }
  }
}

// ---------------- Kernel E: up2 + conv (16->1) + clip, phase-folded ------------
__global__ __launch_bounds__(256) void k_dec2(const float* __restrict__ d1,
                                              const float* __restrict__ fwd2,
                                              const float* __restrict__ bias,
                                              float* __restrict__ out) {
  __shared__ float st[16 * 360];  // [ic][18 rows][20]
  int tid = threadIdx.x;
  int b = blockIdx.y;
  int R0 = (blockIdx.x >> 3) * 16, C0 = (blockIdx.x & 7) * 16;
  const float* ip = d1 + (size_t)b * 262144;
  for (int i = tid; i < 5184; i += 256) {  // 16 ic x 18 x 18
    int ic = i / 324, rr = (i % 324) / 18, cc = i % 18;
    int r = R0 - 1 + rr, c = C0 - 1 + cc;
    st[ic * 360 + rr * 20 + cc] =
        ((unsigned)r < 128u && (unsigned)c < 128u) ? ip[ic * 16384 + r * 128 + c] : 0.f;
  }
  __syncthreads();
  int lane = tid & 63, wid = tid >> 6;
  int qy = wid >> 1, qx = wid & 1;
  int ty = qy * 8 + (lane >> 3), tx = qx * 8 + (lane & 7);
  float acc[4] = {0.f, 0.f, 0.f, 0.f};
#pragma unroll 1
  for (int ic = 0; ic < 16; ++ic) {
    const float* t = st + ic * 360 + ty * 20 + tx;
    float i3[3][3];
#pragma unroll
    for (int dy = 0; dy < 3; ++dy)
#pragma unroll
      for (int dx = 0; dx < 3; ++dx) i3[dy][dx] = t[dy * 20 + dx];
    const float* wp = fwd2 + ic * 16;  // scalar loads
#pragma unroll
    for (int p = 0; p < 4; ++p) {
      int a = p >> 1, b2 = p & 1;
#pragma unroll
      for (int tp = 0; tp < 4; ++tp) {
        int dy = tp >> 1, dx = tp & 1;
        acc[p] = fmaf(i3[a + dy][b2 + dx], wp[p * 4 + tp], acc[p]);
      }
    }
  }
  float bv = bias[0];
  int Y = 2 * (R0 + ty), X = 2 * (C0 + tx);
  float* op = out + (size_t)b * 65536 + Y * 256 + X;
  float2 r0v, r1v;
  r0v.x = fminf(1.0f, fmaxf(-1.0f, acc[0] + bv));
  r0v.y = fminf(1.0f, fmaxf(-1.0f, acc[1] + bv));
  r1v.x = fminf(1.0f, fmaxf(-1.0f, acc[2] + bv));
  r1v.y = fminf(1.0f, fmaxf(-1.0f, acc[3] + bv));
  *(float2*)op = r0v;
  *(float2*)(op + 256) = r1v;
}

extern "C" void kernel_launch(void* const* d_in, const int* in_sizes, int n_in,
                              void* d_out, int out_size, void* d_ws, size_t ws_size,
                              hipStream_t stream) {
  const float* x   = (const float*)d_in[0];
  const float* e1w = (const float*)d_in[1];
  const float* e1b = (const float*)d_in[2];
  const float* e2w = (const float*)d_in[3];
  const float* e2b = (const float*)d_in[4];
  const float* cb  = (const float*)d_in[5];
  const float* d1w = (const float*)d_in[6];
  const float* d1b = (const float*)d_in[7];
  const float* d2w = (const float*)d_in[8];
  const float* d2b = (const float*)d_in[9];

  float* out = (float*)d_out;
  float* y       = out;                       // [32,1,256,256] = 2097152
  float* idxout  = out + 2097152;             // [32,64,64]     = 131072 (as float)
  float* lossout = out + 2097152 + 131072;    // scalar

  float* ws = (float*)d_ws;
  float* h1      = ws;                        // h1t[32][128][128][16] = 8388608
  float* h2      = ws + 8388608;              // [32,32,64,64]   = 4194304
  float* partial = ws + 12582912;             // 512 floats
  float* fwd2    = ws + 12596224;             // 256
  float* d1o     = h1;                        // dec1 output reuses h1 (after vq)

  // Scratch in the y-region of out (written by k_fold, consumed before k_dec2
  // overwrites all of y): cbs 24576f, csqg 512f, wfrag 6912f, wfd1 27648f.
  unsigned short* cbs = (unsigned short*)out;              // 49152 bf16
  float* csqg = out + 24576;                               // 512
  unsigned short* wfrag = (unsigned short*)(out + 25088);  // 13824 bf16
  unsigned short* wfd1 = (unsigned short*)(out + 32000);   // 55296 bf16

  k_fold<<<dim3(337), 256, 0, stream>>>(e2w, d1w, d2w, cb, fwd2, cbs, csqg, wfrag, wfd1);
  k_enc1<<<dim3(2048), 256, 0, stream>>>(x, e1w, e1b, h1);
  k_enc2<<<dim3(2048), 256, 0, stream>>>(h1, wfrag, e2b, h2);
  k_vq<<<dim3(512), 256, 0, stream>>>(h2, cbs, csqg, idxout, partial);
  k_loss<<<dim3(1), 256, 0, stream>>>(partial, lossout);
  k_dec1<<<dim3(16, 32), 256, 0, stream>>>(idxout, cbs, wfd1, d1b, d1o);
  k_dec2<<<dim3(64, 32), 256, 0, stream>>>(d1o, fwd2, d2b, y);
}

// Round 13
// 210.749 us; speedup vs baseline: 1.7031x; 1.0788x over previous
//
#include <hip/hip_runtime.h>
#include <math.h>

#define GELU(v) (0.5f * (v) * (1.0f + erff((v)*0.70710678118654752440f)))

typedef __attribute__((ext_vector_type(8))) short short8;
typedef __attribute__((ext_vector_type(4))) float f32x4;
typedef __attribute__((ext_vector_type(16))) float f32x16;
#define MFMA16 __builtin_amdgcn_mfma_f32_16x16x32_bf16
#define MFMA32 __builtin_amdgcn_mfma_f32_32x32x16_bf16

// Exact 3-way bf16 split of fp32 (24 = 3x8 mantissa bits, truncation):
// v == p1 + p2 + p3 exactly (each pi representable in bf16).
#define SPLIT3(V, U1, U2, U3)                                                  \
  unsigned U1 = __float_as_uint(V) & 0xFFFF0000u;                              \
  float _r1 = (V)-__uint_as_float(U1);                                         \
  unsigned U2 = __float_as_uint(_r1) & 0xFFFF0000u;                            \
  float _r2 = _r1 - __uint_as_float(U2);                                       \
  unsigned U3 = __float_as_uint(_r2) & 0xFFFF0000u;

// ---------------- Setup: fold weights + split codebook/enc2/dec1 weights -------
__global__ __launch_bounds__(256) void k_fold(const float* __restrict__ e2w,
                                              const float* __restrict__ d1w,
                                              const float* __restrict__ d2w,
                                              const float* __restrict__ cb,
                                              float* __restrict__ fwd2,
                                              unsigned short* __restrict__ cbs,
                                              float* __restrict__ csqg,
                                              unsigned short* __restrict__ wfrag,
                                              unsigned short* __restrict__ wfd1) {
  int i = blockIdx.x * 256 + threadIdx.x;
  if (i < 256) {
    int j = i;
    int pt = j & 15, ic = j >> 4;
    int a = pt >> 3, b2 = (pt >> 2) & 1, dy = (pt >> 1) & 1, dx = pt & 1;
    const float* wsrc = d2w + ic * 9;
    float s = 0.f;
    for (int ky = 0; ky < 3; ++ky) {
      int rm = (a == 0) ? (ky == 0 ? 0 : 1) : (ky == 2 ? 1 : 0);
      if (rm != dy) continue;
      for (int kx = 0; kx < 3; ++kx) {
        int cm = (b2 == 0) ? (kx == 0 ? 0 : 1) : (kx == 2 ? 1 : 0);
        if (cm == dx) s += wsrc[ky * 3 + kx];
      }
    }
    fwd2[j] = s;
  } else if (i < 16640) {
    int j = i - 256;  // [0, 16384): code = j>>5, ch = j&31
    float v = cb[j];
    SPLIT3(v, u1, u2, u3)
    cbs[j] = (unsigned short)(u1 >> 16);
    cbs[16384 + j] = (unsigned short)(u2 >> 16);
    cbs[32768 + j] = (unsigned short)(u3 >> 16);
  } else if (i < 17152) {
    int c = i - 16640;
    const float* row = cb + (size_t)c * 32;
    float s = 0.f;
#pragma unroll
    for (int d = 0; d < 32; ++d) s = fmaf(row[d], row[d], s);
    csqg[c] = s;
  } else if (i < 30976) {
    int j = i - 17152;  // [0, 13824)
    int p = j / 4608, rem = j - p * 4608;
    int t = rem >> 9, l2 = (rem >> 3) & 63, jj = rem & 7;
    float v = e2w[((l2 & 31) * 16 + ((l2 >> 5) * 8 + jj)) * 9 + t];
    SPLIT3(v, u1, u2, u3)
    unsigned short r = (p == 0)   ? (unsigned short)(u1 >> 16)
                       : (p == 1) ? (unsigned short)(u2 >> 16)
                                  : (unsigned short)(u3 >> 16);
    wfrag[j] = r;
  } else if (i < 86272) {
    int j = i - 30976;  // [0, 55296)
    int slot = j >> 9, l2 = (j >> 3) & 63, jj = j & 7;
    int cx = slot / 36, rem = slot % 36;
    int r3 = rem / 12, rem2 = rem % 12;
    int kh = rem2 / 6, rem3 = rem2 % 6;
    int pp = rem3 / 3, part = rem3 % 3;
    int c = l2 & 31, hi = l2 >> 5;
    int oc = c & 15, b2 = c >> 4;
    int ic = kh * 16 + hi * 8 + jj;
    int dy = r3 - pp, dx = cx - b2;
    float s = 0.f;
    if ((unsigned)dy < 2u && (unsigned)dx < 2u) {
      const float* wsrc = d1w + (oc * 32 + ic) * 9;
      for (int ky = 0; ky < 3; ++ky) {
        int rm = (pp == 0) ? (ky == 0 ? 0 : 1) : (ky == 2 ? 1 : 0);
        if (rm != dy) continue;
        for (int kx = 0; kx < 3; ++kx) {
          int cm = (b2 == 0) ? (kx == 0 ? 0 : 1) : (kx == 2 ? 1 : 0);
          if (cm == dx) s += wsrc[ky * 3 + kx];
        }
      }
    }
    SPLIT3(s, u1, u2, u3)
    unsigned short r = (part == 0)   ? (unsigned short)(u1 >> 16)
                       : (part == 1) ? (unsigned short)(u2 >> 16)
                                     : (unsigned short)(u3 >> 16);
    wfd1[j] = r;
  }
}

// ---------------- Kernel A: conv1 (1->16) + maxpool2 + gelu --------------------
// XCD-slab mapping (r12-verified).
__global__ __launch_bounds__(256) void k_enc1(const float* __restrict__ x,
                                              const float* __restrict__ w,
                                              const float* __restrict__ bias,
                                              float* __restrict__ h1) {
  int n = blockIdx.x;
  int ysl = n & 7, m = n >> 3;
  int b = m & 31, k = m >> 5;
  int yy = ysl * 16 + k * 2 + (threadIdx.x >> 7);
  int xx = threadIdx.x & 127;
  const float* xp = x + (size_t)b * 65536;
  int r0 = 2 * yy - 1, c0 = 2 * xx - 1;
  float in[4][4];
#pragma unroll
  for (int i = 0; i < 4; ++i) {
    int r = r0 + i;
    bool rv = (unsigned)r < 256u;
#pragma unroll
    for (int j = 0; j < 4; ++j) {
      int c = c0 + j;
      in[i][j] = (rv && (unsigned)c < 256u) ? xp[r * 256 + c] : 0.0f;
    }
  }
  float vout[16];
#pragma unroll
  for (int oc = 0; oc < 16; ++oc) {
    const float* wp = w + oc * 9;  // uniform -> s_load
    float s00 = 0.f, s01 = 0.f, s10 = 0.f, s11 = 0.f;
#pragma unroll
    for (int ky = 0; ky < 3; ++ky)
#pragma unroll
      for (int kx = 0; kx < 3; ++kx) {
        float wv = wp[ky * 3 + kx];
        s00 = fmaf(in[ky][kx], wv, s00);
        s01 = fmaf(in[ky][kx + 1], wv, s01);
        s10 = fmaf(in[ky + 1][kx], wv, s10);
        s11 = fmaf(in[ky + 1][kx + 1], wv, s11);
      }
    float mm = fmaxf(fmaxf(s00, s01), fmaxf(s10, s11)) + bias[oc];
    vout[oc] = GELU(mm);
  }
  float* op = h1 + (size_t)b * 262144 + ((size_t)yy * 128 + xx) * 16;
#pragma unroll
  for (int q = 0; q < 4; ++q) {
    float4 vq;
    vq.x = vout[4 * q + 0]; vq.y = vout[4 * q + 1];
    vq.z = vout[4 * q + 2]; vq.w = vout[4 * q + 3];
    *(float4*)(op + 4 * q) = vq;
  }
}

// ---------------- Kernel B: conv2 (16->32) + maxpool2 via split MFMA -----------
// (r12-verified: granule staging + XCD-matched grid.)
__global__ __launch_bounds__(256) void k_enc2(const float* __restrict__ h1,
                                              const unsigned short* __restrict__ wfrag,
                                              const float* __restrict__ bias,
                                              float* __restrict__ h2) {
  __shared__ __align__(16) unsigned short sA[3 * 2 * 10 * 34 * 8];  // 32640 B
  const int PP = 2 * 10 * 34 * 8;
  int tid = threadIdx.x;
  int n = blockIdx.x;
  int xcd = n & 7, m = n >> 3;
  int ty = xcd * 2 + (m & 1);
  int q0 = m >> 1;
  int b = q0 >> 2, xt = q0 & 3;
  int X0 = xt * 32, Y0 = ty * 8;
  const float* ip = h1 + (size_t)b * 262144;
  for (int g = tid; g < 680; g += 256) {  // pos(340) x ich(2) granule-groups
    int pos = g >> 1, ich = g & 1;
    int yy = pos / 34, xx = pos - yy * 34;
    int y = Y0 - 1 + yy, xg = X0 - 1 + xx;
    float4 v0 = {0.f, 0.f, 0.f, 0.f}, v1 = {0.f, 0.f, 0.f, 0.f};
    if ((unsigned)y < 128u && (unsigned)xg < 128u) {
      const float* sp = ip + ((size_t)y * 128 + xg) * 16 + ich * 8;
      v0 = *(const float4*)(sp);
      v1 = *(const float4*)(sp + 4);
    }
    float vv[8] = {v0.x, v0.y, v0.z, v0.w, v1.x, v1.y, v1.z, v1.w};
    short8 p1, p2, p3;
#pragma unroll
    for (int e = 0; e < 8; ++e) {
      SPLIT3(vv[e], u1, u2, u3)
      p1[e] = (short)(u1 >> 16);
      p2[e] = (short)(u2 >> 16);
      p3[e] = (short)(u3 >> 16);
    }
    int si = ((ich * 10 + yy) * 34 + xx) * 8;
    *(short8*)(sA + si) = p1;
    *(short8*)(sA + PP + si) = p2;
    *(short8*)(sA + 2 * PP + si) = p3;
  }
  __syncthreads();

  int l = tid & 63, w = tid >> 6;
  int xl = l & 31, ich = l >> 5;
  f32x16 acc0[2], acc1[2];
#pragma unroll
  for (int s = 0; s < 2; ++s)
#pragma unroll
    for (int r = 0; r < 16; ++r) { acc0[s][r] = 0.f; acc1[s][r] = 0.f; }

#pragma unroll
  for (int t = 0; t < 9; ++t) {
    int dy = t / 3, dx = t % 3;
    int s = t & 1;
    const unsigned short* wb = wfrag + t * 512 + l * 8;
    short8 bf1 = *(const short8*)(wb);
    short8 bf2 = *(const short8*)(wb + 4608);
    short8 bf3 = *(const short8*)(wb + 9216);
    int g0 = ((ich * 10) + (2 * w + dy)) * 34 + xl + dx;
    const unsigned short* a0p = sA + g0 * 8;
    short8 a01 = *(const short8*)(a0p);
    short8 a02 = *(const short8*)(a0p + PP);
    short8 a03 = *(const short8*)(a0p + 2 * PP);
    const unsigned short* a1p = a0p + 34 * 8;
    short8 a11 = *(const short8*)(a1p);
    short8 a12 = *(const short8*)(a1p + PP);
    short8 a13 = *(const short8*)(a1p + 2 * PP);
    acc0[s] = MFMA32(a01, bf1, acc0[s], 0, 0, 0);
    acc0[s] = MFMA32(a01, bf2, acc0[s], 0, 0, 0);
    acc0[s] = MFMA32(a02, bf1, acc0[s], 0, 0, 0);
    acc0[s] = MFMA32(a02, bf2, acc0[s], 0, 0, 0);
    acc0[s] = MFMA32(a01, bf3, acc0[s], 0, 0, 0);
    acc0[s] = MFMA32(a03, bf1, acc0[s], 0, 0, 0);
    acc1[s] = MFMA32(a11, bf1, acc1[s], 0, 0, 0);
    acc1[s] = MFMA32(a11, bf2, acc1[s], 0, 0, 0);
    acc1[s] = MFMA32(a12, bf1, acc1[s], 0, 0, 0);
    acc1[s] = MFMA32(a12, bf2, acc1[s], 0, 0, 0);
    acc1[s] = MFMA32(a11, bf3, acc1[s], 0, 0, 0);
    acc1[s] = MFMA32(a13, bf1, acc1[s], 0, 0, 0);
  }

  float bv = bias[l & 31];
  int ypool = (Y0 >> 1) + w;
  float* op = h2 + (size_t)b * 131072 + (size_t)(l & 31) * 4096 + ypool * 64 + (X0 >> 1);
#pragma unroll
  for (int k = 0; k < 8; ++k) {
    float e0 = (acc0[0][2 * k] + acc0[1][2 * k]);
    float o0 = (acc0[0][2 * k + 1] + acc0[1][2 * k + 1]);
    float e1 = (acc1[0][2 * k] + acc1[1][2 * k]);
    float o1 = (acc1[0][2 * k + 1] + acc1[1][2 * k + 1]);
    float mm = fmaxf(fmaxf(e0, o0), fmaxf(e1, o1)) + bv;
    int row = ((2 * k) & 3) + 8 * ((2 * k) >> 2) + 4 * ich;
    op[row >> 1] = mm;
  }
}

// ---------------- Kernel C: VQ via exact-split bf16 MFMA (r11 structure) -------
__global__ __launch_bounds__(256) void k_vq(const float* __restrict__ h2,
                                            const unsigned short* __restrict__ cbs,
                                            const float* __restrict__ csqg,
                                            float* __restrict__ idxout,
                                            float* __restrict__ partial) {
  __shared__ __align__(16) unsigned short sA[3 * 256 * 40];  // [part][tok][40]
  __shared__ float sFsq[256];
  __shared__ float sBd[256];
  __shared__ int sBi[256];
  __shared__ float sred[4];
  int tid = threadIdx.x;
  int blk = blockIdx.x;
  int t0 = blk * 256;
  size_t abase = (size_t)(t0 >> 12) * 131072 + (t0 & 4095);

  {
    const float* src = h2 + abase + tid;
    float fsq = 0.f;
#pragma unroll
    for (int g = 0; g < 4; ++g) {
      short8 p1, p2, p3;
#pragma unroll
      for (int e = 0; e < 8; ++e) {
        float v = src[(g * 8 + e) * 4096];
        fsq = fmaf(v, v, fsq);
        SPLIT3(v, u1, u2, u3)
        p1[e] = (short)(u1 >> 16);
        p2[e] = (short)(u2 >> 16);
        p3[e] = (short)(u3 >> 16);
      }
      *(short8*)(sA + (0 * 256 + tid) * 40 + g * 8) = p1;
      *(short8*)(sA + (1 * 256 + tid) * 40 + g * 8) = p2;
      *(short8*)(sA + (2 * 256 + tid) * 40 + g * 8) = p3;
    }
    sFsq[tid] = fsq;
  }
  __syncthreads();

  int l = tid & 63, w = tid >> 6;
  int cl = l & 15, k0 = (l >> 4) * 8;
  short8 af[3][4];
#pragma unroll
  for (int p = 0; p < 3; ++p)
#pragma unroll
    for (int tq = 0; tq < 4; ++tq) {
      int tok = w * 64 + tq * 16 + cl;
      af[p][tq] = *(const short8*)(sA + (p * 256 + tok) * 40 + k0);
    }

  float bd[4][4];
  int bi[4][4];
#pragma unroll
  for (int a = 0; a < 4; ++a)
#pragma unroll
    for (int b = 0; b < 4; ++b) { bd[a][b] = 3.4e38f; bi[a][b] = 0; }

#define LOADB(S, CT)                                                           \
  {                                                                            \
    int col = (CT)*16 + cl;                                                    \
    b1##S = *(const short8*)(cbs + (0 * 512 + col) * 32 + k0);                 \
    b2##S = *(const short8*)(cbs + (1 * 512 + col) * 32 + k0);                 \
    b3##S = *(const short8*)(cbs + (2 * 512 + col) * 32 + k0);                 \
    cq##S = csqg[col];                                                         \
  }
#define COMPUTE(S, CT)                                                         \
  {                                                                            \
    _Pragma("unroll") for (int tq = 0; tq < 4; ++tq) {                         \
      f32x4 acc = {0.f, 0.f, 0.f, 0.f};                                        \
      acc = MFMA16(af[0][tq], b1##S, acc, 0, 0, 0);                            \
      acc = MFMA16(af[0][tq], b2##S, acc, 0, 0, 0);                            \
      acc = MFMA16(af[1][tq], b1##S, acc, 0, 0, 0);                            \
      acc = MFMA16(af[1][tq], b2##S, acc, 0, 0, 0);                            \
      acc = MFMA16(af[0][tq], b3##S, acc, 0, 0, 0);                            \
      acc = MFMA16(af[2][tq], b1##S, acc, 0, 0, 0);                            \
      _Pragma("unroll") for (int i = 0; i < 4; ++i) {                          \
        float d = fmaf(-2.f, acc[i], cq##S);                                   \
        if (d < bd[tq][i]) { bd[tq][i] = d; bi[tq][i] = (CT)*16 + cl; }        \
      }                                                                        \
    }                                                                          \
  }

  short8 b1A, b2A, b3A, b1B, b2B, b3B;
  float cqA, cqB;
  LOADB(A, 0)
  LOADB(B, 1)
#pragma unroll 1
  for (int ct = 0; ct < 32; ct += 2) {
    COMPUTE(A, ct)
    LOADB(A, (ct + 2) & 31)  // distance-2 prefetch; wrap: in-bounds, unused
    COMPUTE(B, ct + 1)
    LOADB(B, (ct + 3) & 31)
  }
#undef LOADB
#undef COMPUTE

#pragma unroll
  for (int tq = 0; tq < 4; ++tq)
#pragma unroll
    for (int i = 0; i < 4; ++i)
#pragma unroll
      for (int m = 1; m < 16; m <<= 1) {
        float od = __shfl_xor(bd[tq][i], m, 64);
        int ob = __shfl_xor(bi[tq][i], m, 64);
        if (od < bd[tq][i] || (od == bd[tq][i] && ob < bi[tq][i])) {
          bd[tq][i] = od;
          bi[tq][i] = ob;
        }
      }
  if (cl == 0) {
#pragma unroll
    for (int tq = 0; tq < 4; ++tq)
#pragma unroll
      for (int i = 0; i < 4; ++i) {
        int tokl = w * 64 + tq * 16 + (l >> 4) * 4 + i;
        sBi[tokl] = bi[tq][i];
        sBd[tokl] = bd[tq][i];
      }
  }
  __syncthreads();

  idxout[t0 + tid] = (float)sBi[tid];
  float loss = sBd[tid] + sFsq[tid];  // ||q-f||^2 = csq - 2 f.c + ||f||^2
#pragma unroll
  for (int off = 32; off > 0; off >>= 1) loss += __shfl_down(loss, off, 64);
  if (l == 0) sred[w] = loss;
  __syncthreads();
  if (tid == 0) partial[blk] = (sred[0] + sred[1]) + (sred[2] + sred[3]);
}

// ---------------- Kernel F: finalize commit loss (512 partials) ----------------
__global__ __launch_bounds__(256) void k_loss(const float* __restrict__ partial,
                                              float* __restrict__ lossout) {
  __shared__ float sred[4];
  int tid = threadIdx.x;
  float v = partial[tid] + partial[tid + 256];
#pragma unroll
  for (int off = 32; off > 0; off >>= 1) v += __shfl_down(v, off, 64);
  if ((tid & 63) == 0) sred[tid >> 6] = v;
  __syncthreads();
  if (tid == 0)
    lossout[0] = ((sred[0] + sred[1]) + (sred[2] + sred[3])) * (1.0f / 4194304.0f);
}

// ---------------- Kernel D: up2 + conv (32->16) + gelu via split MFMA ----------
// r13: (a) NO LDS A-staging — A-frags gathered per-lane directly from L2-hot
// cbs (16B at (part*512+idx)*32 + kh*16 + hi*8); only sIdx (204 ints) in LDS.
// (b) 1 q-row per wave: 1024 blocks x 4 waves = 16 waves/CU (2x TLP), acc 32reg.
// (c) output layout d1o[y][x][ic16] (interleaved): wave stores = 4x64B chunks.
__global__ __launch_bounds__(256) void k_dec1(const float* __restrict__ idxf,
                                              const unsigned short* __restrict__ cbs,
                                              const unsigned short* __restrict__ wfd1,
                                              const float* __restrict__ bias,
                                              float* __restrict__ o) {
  __shared__ int sIdx[204];  // 6 halo rows x 34 cols
  int tid = threadIdx.x;
  int b = blockIdx.y;
  int qx0 = (blockIdx.x & 1) * 32, qy0 = (blockIdx.x >> 1) * 4;
  const float* ib = idxf + (size_t)b * 4096;
  if (tid < 204) {
    int yy = tid / 34, xx = tid % 34;
    int y = qy0 - 1 + yy, x = qx0 - 1 + xx;
    sIdx[tid] = ((unsigned)y < 64u && (unsigned)x < 64u) ? (int)ib[y * 64 + x] : -1;
  }
  __syncthreads();

  int l = tid & 63, w = tid >> 6;  // wave w -> output q-row qy0+w
  int xl = l & 31, hi = l >> 5;
  f32x16 acc[2];  // [p2 = output row phase]
#pragma unroll
  for (int p2 = 0; p2 < 2; ++p2)
#pragma unroll
    for (int r = 0; r < 16; ++r) acc[p2][r] = 0.f;

#pragma unroll
  for (int cx = 0; cx < 3; ++cx) {
#pragma unroll
    for (int kh = 0; kh < 2; ++kh) {
      short8 Bf[4][3];  // q=(ry,pq) packed: 0:(0,0) 1:(1,0) 2:(1,1) 3:(2,1)
#pragma unroll
      for (int q = 0; q < 4; ++q) {
        int r3 = (q == 0) ? 0 : (q == 3) ? 2 : 1;
        int pq = (q >= 2) ? 1 : 0;
#pragma unroll
        for (int pt = 0; pt < 3; ++pt) {
          int slot = cx * 36 + r3 * 12 + kh * 6 + pq * 3 + pt;
          Bf[q][pt] = *(const short8*)(wfd1 + (size_t)slot * 512 + l * 8);
        }
      }
#pragma unroll
      for (int ry = 0; ry < 3; ++ry) {
        int idx = sIdx[(w + ry) * 34 + xl + cx];
        short8 a1 = {0, 0, 0, 0, 0, 0, 0, 0};
        short8 a2 = {0, 0, 0, 0, 0, 0, 0, 0};
        short8 a3 = {0, 0, 0, 0, 0, 0, 0, 0};
        if (idx >= 0) {
          const unsigned short* ap = cbs + (size_t)idx * 32 + kh * 16 + hi * 8;
          a1 = *(const short8*)(ap);
          a2 = *(const short8*)(ap + 16384);
          a3 = *(const short8*)(ap + 32768);
        }
#pragma unroll
        for (int p2 = 0; p2 < 2; ++p2) {
          if ((ry == 0 && p2 == 1) || (ry == 2 && p2 == 0)) continue;
          int q = ry + p2;
          f32x16 t = acc[p2];
          t = MFMA32(a1, Bf[q][0], t, 0, 0, 0);
          t = MFMA32(a1, Bf[q][1], t, 0, 0, 0);
          t = MFMA32(a2, Bf[q][0], t, 0, 0, 0);
          t = MFMA32(a2, Bf[q][1], t, 0, 0, 0);
          t = MFMA32(a1, Bf[q][2], t, 0, 0, 0);
          t = MFMA32(a3, Bf[q][0], t, 0, 0, 0);
          acc[p2] = t;
        }
      }
    }
  }

  // epilogue: D row = qpos_x = (reg&3)+8*(reg>>2)+4*hi; col c=l&31 -> b2,oc.
  // interleaved store: [Y][X][ic16] -> 16 oc lanes contiguous (64B chunks).
  float bv = bias[l & 15];
  int b2 = (l >> 4) & 1;
  int oc = l & 15;
  int qy = qy0 + w;
  float* ob = o + (size_t)b * 262144;
#pragma unroll
  for (int p2 = 0; p2 < 2; ++p2) {
    int Y = 2 * qy + p2;
#pragma unroll
    for (int reg = 0; reg < 16; ++reg) {
      int rowval = (reg & 3) + 8 * (reg >> 2) + 4 * hi;
      int X = qx0 * 2 + 2 * rowval + b2;
      ob[((size_t)Y * 128 + X) * 16 + oc] = GELU(acc[p2][reg] + bv);
    }
  }
}

// ---------------- Kernel E: up2 + conv (16->1) + clip, phase-folded ------------
// r13: input d1o now interleaved [y][x][ic16]; LDS position-major [pos][17]
// (odd stride -> conflict-free); staging reads are 64B-contiguous float4s.
__device__ __forceinline__ void d2_loadi3(float (&dst)[3][3], const float* t) {
#pragma unroll
  for (int dy = 0; dy < 3; ++dy)
#pragma unroll
    for (int dx = 0; dx < 3; ++dx) dst[dy][dx] = t[(dy * 18 + dx) * 17];
}
__global__ __launch_bounds__(256) void k_dec2(const float* __restrict__ d1,
                                              const float* __restrict__ fwd2,
                                              const float* __restrict__ bias,
                                              float* __restrict__ out) {
  __shared__ float st[18 * 18 * 17];  // [row][col][ic16 + pad]
  int tid = threadIdx.x;
  int b = blockIdx.y;
  int R0 = (blockIdx.x >> 3) * 16, C0 = (blockIdx.x & 7) * 16;
  const float* ip = d1 + (size_t)b * 262144;
  for (int i = tid; i < 1296; i += 256) {  // 324 pos x 4 ic-quads
    int pos = i >> 2, q = i & 3;
    int rr = pos / 18, cc = pos % 18;
    int r = R0 - 1 + rr, c = C0 - 1 + cc;
    float4 v = {0.f, 0.f, 0.f, 0.f};
    if ((unsigned)r < 128u && (unsigned)c < 128u)
      v = *(const float4*)(ip + ((size_t)r * 128 + c) * 16 + q * 4);
    float* dp = st + (rr * 18 + cc) * 17 + q * 4;
    dp[0] = v.x; dp[1] = v.y; dp[2] = v.z; dp[3] = v.w;
  }
  __syncthreads();
  int lane = tid & 63, wid = tid >> 6;
  int qy = wid >> 1, qx = wid & 1;
  int ty = qy * 8 + (lane >> 3), tx = qx * 8 + (lane & 7);
  float acc[4] = {0.f, 0.f, 0.f, 0.f};
  const float* tb = st + (ty * 18 + tx) * 17;
  float i3A[3][3], i3B[3][3];
  d2_loadi3(i3A, tb);
#pragma unroll 1
  for (int ic = 0; ic < 16; ic += 2) {
    d2_loadi3(i3B, tb + (ic + 1));
    {
      const float* wp = fwd2 + ic * 16;  // scalar loads
#pragma unroll
      for (int p = 0; p < 4; ++p) {
        int a = p >> 1, b2 = p & 1;
#pragma unroll
        for (int tp = 0; tp < 4; ++tp) {
          int dy = tp >> 1, dx = tp & 1;
          acc[p] = fmaf(i3A[a + dy][b2 + dx], wp[p * 4 + tp], acc[p]);
        }
      }
    }
    d2_loadi3(i3A, tb + ((ic + 2) & 15));  // wrap: harmless re-read
    {
      const float* wp = fwd2 + (ic + 1) * 16;
#pragma unroll
      for (int p = 0; p < 4; ++p) {
        int a = p >> 1, b2 = p & 1;
#pragma unroll
        for (int tp = 0; tp < 4; ++tp) {
          int dy = tp >> 1, dx = tp & 1;
          acc[p] = fmaf(i3B[a + dy][b2 + dx], wp[p * 4 + tp], acc[p]);
        }
      }
    }
  }
  float bv = bias[0];
  int Y = 2 * (R0 + ty), X = 2 * (C0 + tx);
  float* op = out + (size_t)b * 65536 + Y * 256 + X;
  float2 r0v, r1v;
  r0v.x = fminf(1.0f, fmaxf(-1.0f, acc[0] + bv));
  r0v.y = fminf(1.0f, fmaxf(-1.0f, acc[1] + bv));
  r1v.x = fminf(1.0f, fmaxf(-1.0f, acc[2] + bv));
  r1v.y = fminf(1.0f, fmaxf(-1.0f, acc[3] + bv));
  *(float2*)op = r0v;
  *(float2*)(op + 256) = r1v;
}

extern "C" void kernel_launch(void* const* d_in, const int* in_sizes, int n_in,
                              void* d_out, int out_size, void* d_ws, size_t ws_size,
                              hipStream_t stream) {
  const float* x   = (const float*)d_in[0];
  const float* e1w = (const float*)d_in[1];
  const float* e1b = (const float*)d_in[2];
  const float* e2w = (const float*)d_in[3];
  const float* e2b = (const float*)d_in[4];
  const float* cb  = (const float*)d_in[5];
  const float* d1w = (const float*)d_in[6];
  const float* d1b = (const float*)d_in[7];
  const float* d2w = (const float*)d_in[8];
  const float* d2b = (const float*)d_in[9];

  float* out = (float*)d_out;
  float* y       = out;                       // [32,1,256,256] = 2097152
  float* idxout  = out + 2097152;             // [32,64,64]     = 131072 (as float)
  float* lossout = out + 2097152 + 131072;    // scalar

  float* ws = (float*)d_ws;
  float* h1      = ws;                        // h1t[32][128][128][16] = 8388608
  float* h2      = ws + 8388608;              // [32,32,64,64]   = 4194304
  float* partial = ws + 12582912;             // 512 floats
  float* fwd2    = ws + 12596224;             // 256
  float* d1o     = h1;  // d1o[32][128][128][16] interleaved, reuses h1 (after vq)

  // Scratch in the y-region of out (written by k_fold, consumed before k_dec2
  // overwrites all of y): cbs 24576f, csqg 512f, wfrag 6912f, wfd1 27648f.
  unsigned short* cbs = (unsigned short*)out;              // 49152 bf16
  float* csqg = out + 24576;                               // 512
  unsigned short* wfrag = (unsigned short*)(out + 25088);  // 13824 bf16
  unsigned short* wfd1 = (unsigned short*)(out + 32000);   // 55296 bf16

  k_fold<<<dim3(337), 256, 0, stream>>>(e2w, d1w, d2w, cb, fwd2, cbs, csqg, wfrag, wfd1);
  k_enc1<<<dim3(2048), 256, 0, stream>>>(x, e1w, e1b, h1);
  k_enc2<<<dim3(2048), 256, 0, stream>>>(h1, wfrag, e2b, h2);
  k_vq<<<dim3(512), 256, 0, stream>>>(h2, cbs, csqg, idxout, partial);
  k_loss<<<dim3(1), 256, 0, stream>>>(partial, lossout);
  k_dec1<<<dim3(32, 32), 256, 0, stream>>>(idxout, cbs, wfd1, d1b, d1o);
  k_dec2<<<dim3(64, 32), 256, 0, stream>>>(d1o, fwd2, d2b, y);
}